// Round 4
// baseline (1012.980 us; speedup 1.0000x reference)
//
#include <hip/hip_runtime.h>
#include <cstdint>

#define B_  2
#define S_  1024
#define H_  1024
#define NH_ 16
#define DH_ 64
#define F_  4096
#define L_  4
#define M_  (B_*S_)        // 2048 rows in all GEMMs
#define BHS_ (B_*NH_*S_)   // 32768 (b,h,s) rows in attention

typedef __bf16 bf16;
typedef __bf16 bf16x8 __attribute__((ext_vector_type(8)));
typedef __bf16 bf16x4 __attribute__((ext_vector_type(4)));
typedef __bf16 bf16x2 __attribute__((ext_vector_type(2)));
typedef float  f32x4  __attribute__((ext_vector_type(4)));

// ---------------- async global->LDS (16B per lane), CK-style addrspace cast ----
__device__ __forceinline__ void async_ld16(void* lds, const void* g) {
  auto* lp = reinterpret_cast<__attribute__((address_space(3))) unsigned int*>(
      reinterpret_cast<uintptr_t>(lds));
  const auto* gp = reinterpret_cast<const __attribute__((address_space(1))) unsigned int*>(
      reinterpret_cast<uintptr_t>(g));
  __builtin_amdgcn_global_load_lds(gp, lp, 16, 0, 0);
}

__device__ __forceinline__ float gelu_tanh(float x) {
  float u = 0.7978845608028654f * (x + 0.044715f * x * x * x);
  u = fminf(fmaxf(u, -15.f), 15.f);
  float e = __builtin_amdgcn_exp2f(u * 2.8853900817779268f); // exp(2u)
  return 0.5f * x * (1.f + (e - 1.f) / (e + 1.f));
}

// ---------------- weight transpose + fp32->bf16 convert:  W[K][N] -> Wt[N][K] --
__global__ __launch_bounds__(256) void transpose_cvt(
    const float* __restrict__ src, bf16* __restrict__ dst, int K, int N,
    size_t src_z, size_t dst_z) {
  __shared__ float t[32][33];
  const int n0 = blockIdx.x * 32, k0 = blockIdx.y * 32;
  const size_t so = (size_t)blockIdx.z * src_z;
  const size_t dо = (size_t)blockIdx.z * dst_z;
  const int x = threadIdx.x, y = threadIdx.y;
  #pragma unroll
  for (int i = 0; i < 32; i += 8)
    t[y + i][x] = src[so + (size_t)(k0 + y + i) * N + n0 + x];
  __syncthreads();
  #pragma unroll
  for (int i = 0; i < 32; i += 8)
    dst[dо + (size_t)(n0 + y + i) * K + k0 + x] = (bf16)t[x][y + i];
}

// ---------------- mask -> bf16 additive adder in log2 domain ------------------
__global__ __launch_bounds__(256) void mask_cvt(
    const float4* __restrict__ m, bf16x4* __restrict__ out) {
  const int i = blockIdx.x * 256 + (int)threadIdx.x;
  const float c2 = -10000.f * 1.44269504088896f;
  float4 v = m[i];
  bf16x4 o;
  o[0] = (bf16)((1.f - v.x) * c2);
  o[1] = (bf16)((1.f - v.y) * c2);
  o[2] = (bf16)((1.f - v.z) * c2);
  o[3] = (bf16)((1.f - v.w) * c2);
  out[i] = o;
}

// ---------------- x init: copy fp32 x -> xf (running x, = d_out) + bf16 mirror -
__global__ __launch_bounds__(256) void init_x_kernel(
    const float4* __restrict__ x, float4* __restrict__ xf, bf16x4* __restrict__ xb) {
  int i = blockIdx.x * 256 + threadIdx.x;
  float4 v = x[i];
  xf[i] = v;
  bf16x4 b;
  b[0] = (bf16)v.x; b[1] = (bf16)v.y; b[2] = (bf16)v.z; b[3] = (bf16)v.w;
  xb[i] = b;
}

// ---------------- m97-structure GEMM core: C[128x128] = A[.][ld] @ Bt[.][ld]^T -
__device__ __forceinline__ void gemm_core(
    const bf16* __restrict__ A, const bf16* __restrict__ Bt, int ld, int kLen,
    int m0, int n0, bf16* As, bf16* Bs, f32x4 (&acc)[4][4]) {
  const int tid = (int)threadIdx.x;
  const int w = tid >> 6, l = tid & 63;
  const int lr = l & 15, lg = l >> 4;
  const int wm = w >> 1, wn = w & 1;
  const int srow = l >> 2;            // 0..15 (staging row within 16-row chunk)
  const int scol = (l & 3) * 8;       // element offset (8 bf16 = 16B)

  const bf16* ag = A  + (size_t)(m0 + w * 32 + srow) * ld + scol;
  const bf16* bg = Bt + (size_t)(n0 + w * 32 + srow) * ld + scol;
  bf16* asd = As + (w * 32) * 32;
  bf16* bsd = Bs + (w * 32) * 32;

  for (int k0 = 0; k0 < kLen; k0 += 32) {
    __syncthreads();                  // prior frag reads done before overwrite
    async_ld16(asd,            ag);
    async_ld16(asd + 16 * 32,  ag + (size_t)16 * ld);
    async_ld16(bsd,            bg);
    async_ld16(bsd + 16 * 32,  bg + (size_t)16 * ld);
    ag += 32; bg += 32;
    __syncthreads();                  // vmcnt(0) drain: LDS tiles ready
    bf16x8 af[4], bv[4];
    #pragma unroll
    for (int i = 0; i < 4; ++i)
      af[i] = *(const bf16x8*)(As + (wm * 64 + i * 16 + lr) * 32 + lg * 8);
    #pragma unroll
    for (int i = 0; i < 4; ++i)
      bv[i] = *(const bf16x8*)(Bs + (wn * 64 + i * 16 + lr) * 32 + lg * 8);
    #pragma unroll
    for (int i = 0; i < 4; ++i)
      #pragma unroll
      for (int j = 0; j < 4; ++j)
        acc[i][j] = __builtin_amdgcn_mfma_f32_16x16x32_bf16(af[i], bv[j], acc[i][j], 0, 0, 0);
  }
}

// MODE 0: out_bf16 = acc+bias | MODE 1: out_bf16 = gelu(acc+bias)
// MODE 2: xf += alpha*(acc+bias) (fp32, in-place) and xb = bf16(xf)
// MODE 3: fp32 partial (no bias) -> part[z*M*N + idx]
// MODE 4: bf16 partial (no bias) -> outb[z*M*N + idx]
template <int MODE>
__global__ __launch_bounds__(256) void gemm128_kernel(
    const bf16* __restrict__ A, const bf16* __restrict__ Bt,
    const float* __restrict__ bias, bf16* __restrict__ outb,
    float* __restrict__ outf, const float* __restrict__ alphap,
    float* __restrict__ part, int N, int K, int kSlice) {
  __shared__ __align__(16) bf16 As[128 * 32];
  __shared__ __align__(16) bf16 Bs[128 * 32];
  const int m0 = blockIdx.y * 128, n0 = blockIdx.x * 128;
  const int z = blockIdx.z;
  const f32x4 z4 = {0.f, 0.f, 0.f, 0.f};
  f32x4 acc[4][4];
  #pragma unroll
  for (int i = 0; i < 4; ++i)
    #pragma unroll
    for (int j = 0; j < 4; ++j) acc[i][j] = z4;

  gemm_core(A + (size_t)z * kSlice, Bt + (size_t)z * kSlice, K, kSlice,
            m0, n0, As, Bs, acc);

  const int tid = (int)threadIdx.x;
  const int w = tid >> 6, l = tid & 63;
  const int lr = l & 15, lg = l >> 4;
  const int wm = w >> 1, wn = w & 1;
  float alpha = 0.f;
  if (MODE == 2) alpha = *alphap;
  const size_t pbase = (MODE >= 3) ? (size_t)z * M_ * (size_t)N : 0;
  #pragma unroll
  for (int i = 0; i < 4; ++i) {
    const int row0 = m0 + wm * 64 + i * 16 + lg * 4;
    #pragma unroll
    for (int j = 0; j < 4; ++j) {
      const int col = n0 + wn * 64 + j * 16 + lr;
      const float bvx = (MODE >= 3) ? 0.f : bias[col];
      #pragma unroll
      for (int r = 0; r < 4; ++r) {
        const size_t idx = (size_t)(row0 + r) * N + col;
        float v = acc[i][j][r] + bvx;
        if (MODE == 3) {
          part[pbase + idx] = v;
        } else if (MODE == 4) {
          outb[pbase + idx] = (bf16)v;
        } else if (MODE == 1) {
          outb[idx] = (bf16)gelu_tanh(v);
        } else if (MODE == 2) {
          float xn = outf[idx] + alpha * v;
          outf[idx] = xn;
          outb[idx] = (bf16)xn;
        } else {
          outb[idx] = (bf16)v;
        }
      }
    }
  }
}

// ---------------- split-K reduce + bias + ReZero residual (fp32 partials, z=4) -
__global__ __launch_bounds__(256) void reduce_residual(
    const float4* __restrict__ part, const float* __restrict__ bias,
    const float* __restrict__ alphap, float4* __restrict__ xf,
    bf16x4* __restrict__ xb) {
  const int i = blockIdx.x * 256 + (int)threadIdx.x;   // over M_*H_/4
  const int nper = M_ * H_ / 4;
  float4 s = part[i];
  #pragma unroll
  for (int zz = 1; zz < 4; ++zz) {
    float4 p = part[i + (size_t)zz * nper];
    s.x += p.x; s.y += p.y; s.z += p.z; s.w += p.w;
  }
  const int col = (i * 4) & (H_ - 1);
  const float4 b4 = *(const float4*)(bias + col);
  const float a = *alphap;
  float4 xv = xf[i];
  xv.x += a * (s.x + b4.x);
  xv.y += a * (s.y + b4.y);
  xv.z += a * (s.z + b4.z);
  xv.w += a * (s.w + b4.w);
  xf[i] = xv;
  bf16x4 bb;
  bb[0] = (bf16)xv.x; bb[1] = (bf16)xv.y; bb[2] = (bf16)xv.z; bb[3] = (bf16)xv.w;
  xb[i] = bb;
}

// ---------------- QKV combine: sum 2 bf16 partials + bias; route Q/K/Vt -------
__global__ __launch_bounds__(256) void qkv_combine(
    const bf16x4* __restrict__ pb, const float* __restrict__ bq,
    const float* __restrict__ bk, const float* __restrict__ bv,
    bf16* __restrict__ qo, bf16* __restrict__ ko, bf16* __restrict__ vt) {
  const int i = blockIdx.x * 256 + (int)threadIdx.x;   // over M_*3072/4
  const int row = i / 768;
  const int c4 = (i - row * 768) * 4;
  const bf16x4 p0 = pb[i];
  const bf16x4 p1 = pb[i + M_ * 3072 / 4];
  float s[4];
  #pragma unroll
  for (int k = 0; k < 4; ++k) s[k] = (float)p0[k] + (float)p1[k];
  if (c4 < 1024) {
    const float4 b4 = *(const float4*)(bq + c4);
    bf16x4 o;
    o[0]=(bf16)(s[0]+b4.x); o[1]=(bf16)(s[1]+b4.y);
    o[2]=(bf16)(s[2]+b4.z); o[3]=(bf16)(s[3]+b4.w);
    *(bf16x4*)(qo + (size_t)row * H_ + c4) = o;
  } else if (c4 < 2048) {
    const int c = c4 - 1024;
    const float4 b4 = *(const float4*)(bk + c);
    bf16x4 o;
    o[0]=(bf16)(s[0]+b4.x); o[1]=(bf16)(s[1]+b4.y);
    o[2]=(bf16)(s[2]+b4.z); o[3]=(bf16)(s[3]+b4.w);
    *(bf16x4*)(ko + (size_t)row * H_ + c) = o;
  } else {
    const int d0 = c4 - 2048;
    const float4 b4 = *(const float4*)(bv + d0);
    const int hh = d0 >> 6, dd = d0 & 63;
    const int bb = row >> 10, ss = row & (S_ - 1);
    const size_t base = (((size_t)(bb * NH_ + hh) * DH_ + dd) << 10) + ss;
    vt[base]              = (bf16)(s[0] + b4.x);
    vt[base + 1024]       = (bf16)(s[1] + b4.y);
    vt[base + 2048]       = (bf16)(s[2] + b4.z);
    vt[base + 3072]       = (bf16)(s[3] + b4.w);
  }
}

// ---------------- FFN1 combine: sum 2 bf16 partials + bias -> gelu -> itm -----
__global__ __launch_bounds__(256) void ffn1_combine(
    const bf16x4* __restrict__ pb, const float* __restrict__ bias,
    bf16x4* __restrict__ itm) {
  const int i = blockIdx.x * 256 + (int)threadIdx.x;   // over M_*F_/4
  const int c4 = (i & 1023) * 4;
  const bf16x4 p0 = pb[i];
  const bf16x4 p1 = pb[i + M_ * F_ / 4];
  const float4 b4 = *(const float4*)(bias + c4);
  bf16x4 o;
  o[0] = (bf16)gelu_tanh((float)p0[0] + (float)p1[0] + b4.x);
  o[1] = (bf16)gelu_tanh((float)p0[1] + (float)p1[1] + b4.y);
  o[2] = (bf16)gelu_tanh((float)p0[2] + (float)p1[2] + b4.z);
  o[3] = (bf16)gelu_tanh((float)p0[3] + (float)p1[3] + b4.w);
  itm[i] = o;
}

// ---------------- flash attention v3: swapped QK^T, lane-local softmax --------
// grid (S/64, NH, B*2), 256 thr = 4 waves, 16 q-rows/wave, KVBLK=64, kv-split=2.
// Lane (lr,lg) after mfma(K,Q): holds scores[kv=16t+4lg+r][q=lr] -> softmax is
// 15 local VALU ops + 2 shuffles. PV computed transposed: acc=mfma(Vt,P).
__global__ __launch_bounds__(256) void attn_kernel3(
    const bf16* __restrict__ Q, const bf16* __restrict__ Kb,
    const bf16* __restrict__ Vt, const bf16* __restrict__ madd,
    float* __restrict__ pctx, float* __restrict__ pm, float* __restrict__ pl) {
  const int tid = (int)threadIdx.x;
  const int w = tid >> 6, l = tid & 63;
  const int lr = l & 15, lg = l >> 4;
  const int h = blockIdx.y;
  const int b = blockIdx.z >> 1, half = blockIdx.z & 1;
  const int q0 = blockIdx.x * 64 + w * 16;
  const int kvbase = half * (S_ / 2), kvend = kvbase + S_ / 2;

  // per-wave P buffer: u32-packed bf16 pairs. row=q (lr), col=kv-pair idx.
  // row stride 36 u32 (144B, 16B-aligned for b128 reads).
  __shared__ unsigned int Pu[4][16][36];

  const bf16* qp = Q + ((size_t)(b * S_ + q0 + lr)) * H_ + h * DH_;
  const bf16x8 qa0 = *(const bf16x8*)(qp + lg * 8);
  const bf16x8 qa1 = *(const bf16x8*)(qp + 32 + lg * 8);

  const f32x4 z4 = {0.f, 0.f, 0.f, 0.f};
  f32x4 acc[4];
  #pragma unroll
  for (int dt = 0; dt < 4; ++dt) acc[dt] = z4;
  float mrow = -1e30f, ssum = 0.f;

  const bf16* Kbase = Kb + ((size_t)b * S_) * H_ + h * DH_;
  const bf16* Vbase = Vt + ((size_t)(b * NH_ + h)) * DH_ * S_;
  const bf16* Mb = madd + ((size_t)(b * S_ + q0 + lr)) * S_;

  const float c1 = 0.125f * 1.44269504088896f;   // scale * log2(e)
  const float THR = 10.f;                        // defer-max headroom (base-2)

  for (int kv0 = kvbase; kv0 < kvend; kv0 += 64) {
    // --- load K frags + mask adders (hoisted; independent) ------------------
    bf16x8 kf0[4], kf1[4];
    bf16x4 mk[4];
    #pragma unroll
    for (int t = 0; t < 4; ++t) {
      const bf16* kp = Kbase + (size_t)(kv0 + t * 16 + lr) * H_;
      kf0[t] = *(const bf16x8*)(kp + lg * 8);
      kf1[t] = *(const bf16x8*)(kp + 32 + lg * 8);
      mk[t] = *(const bf16x4*)(Mb + kv0 + t * 16 + lg * 4);
    }
    // --- QK^T swapped: st[t][r] = scores[kv=16t+4lg+r][q=lr] ----------------
    f32x4 st[4];
    __builtin_amdgcn_s_setprio(1);
    #pragma unroll
    for (int t = 0; t < 4; ++t) {
      f32x4 s = __builtin_amdgcn_mfma_f32_16x16x32_bf16(kf0[t], qa0, z4, 0, 0, 0);
      st[t] = __builtin_amdgcn_mfma_f32_16x16x32_bf16(kf1[t], qa1, s, 0, 0, 0);
    }
    __builtin_amdgcn_s_setprio(0);
    // --- scale + mask (base-2 domain), lane-local ---------------------------
    float sv[4][4];
    #pragma unroll
    for (int t = 0; t < 4; ++t)
      #pragma unroll
      for (int r = 0; r < 4; ++r)
        sv[t][r] = st[t][r] * c1 + (float)mk[t][r];
    // --- row max: 15 local fmax + 2 shuffles --------------------------------
    float nm = sv[0][0];
    #pragma unroll
    for (int t = 0; t < 4; ++t)
      #pragma unroll
      for (int r = 0; r < 4; ++r) nm = fmaxf(nm, sv[t][r]);
    nm = fmaxf(nm, __shfl_xor(nm, 16));
    nm = fmaxf(nm, __shfl_xor(nm, 32));
    // --- defer-max rescale --------------------------------------------------
    if (__any(nm > mrow + THR)) {
      float newm = fmaxf(mrow, nm);
      float f = __builtin_amdgcn_exp2f(mrow - newm);
      mrow = newm;
      ssum *= f;
      #pragma unroll
      for (int dt = 0; dt < 4; ++dt)
        #pragma unroll
        for (int r = 0; r < 4; ++r) acc[dt][r] *= f;
    }
    // --- P = 2^(sv - mrow); local sum + 2 shuffles --------------------------
    float p[4][4];
    float ps = 0.f;
    #pragma unroll
    for (int t = 0; t < 4; ++t)
      #pragma unroll
      for (int r = 0; r < 4; ++r) {
        p[t][r] = __builtin_amdgcn_exp2f(sv[t][r] - mrow);
        ps += p[t][r];
      }
    ps += __shfl_xor(ps, 16);
    ps += __shfl_xor(ps, 32);
    ssum += ps;
    // --- pack P to LDS as u32 bf16-pairs: idx = kvpair/2 = 8t+2lg+h ---------
    #pragma unroll
    for (int t = 0; t < 4; ++t)
      #pragma unroll
      for (int hh = 0; hh < 2; ++hh) {
        union { bf16x2 v; unsigned int u; } pk;
        pk.v[0] = (bf16)p[t][2 * hh];
        pk.v[1] = (bf16)p[t][2 * hh + 1];
        Pu[w][lr][8 * t + 2 * lg + hh] = pk.u;
      }
    // --- read B-frags: chunk c -> u32 idx 16c+4lg..+3 (contiguous b128) -----
    const bf16x8 pf0 = *(const bf16x8*)&Pu[w][lr][4 * lg];
    const bf16x8 pf1 = *(const bf16x8*)&Pu[w][lr][16 + 4 * lg];
    // --- PV transposed: acc[dt][r] = ctx^T[d=16dt+4lg+r][q=lr] --------------
    __builtin_amdgcn_s_setprio(1);
    #pragma unroll
    for (int dt = 0; dt < 4; ++dt) {
      bf16x8 vb0 = *(const bf16x8*)(Vbase + (size_t)(dt * 16 + lr) * S_ + kv0 + lg * 8);
      acc[dt] = __builtin_amdgcn_mfma_f32_16x16x32_bf16(vb0, pf0, acc[dt], 0, 0, 0);
    }
    #pragma unroll
    for (int dt = 0; dt < 4; ++dt) {
      bf16x8 vb1 = *(const bf16x8*)(Vbase + (size_t)(dt * 16 + lr) * S_ + kv0 + 32 + lg * 8);
      acc[dt] = __builtin_amdgcn_mfma_f32_16x16x32_bf16(vb1, pf1, acc[dt], 0, 0, 0);
    }
    __builtin_amdgcn_s_setprio(0);
  }
  // --- write unnormalized partials (lane owns q-row = lr) -------------------
  const int gq = (b * NH_ + h) * S_ + q0 + lr;
  const size_t rowi = (size_t)half * BHS_ + gq;
  #pragma unroll
  for (int dt = 0; dt < 4; ++dt)
    *(f32x4*)(pctx + rowi * 64 + dt * 16 + lg * 4) = acc[dt];
  if (lg == 0) { pm[rowi] = mrow; pl[rowi] = ssum; }
}

// ---------------- combine the two kv-halves -> ctx bf16 ----------------------
__global__ __launch_bounds__(256) void attn_combine(
    const float4* __restrict__ pctx, const float* __restrict__ pm,
    const float* __restrict__ pl, bf16* __restrict__ Ctx) {
  const int i = blockIdx.x * 256 + (int)threadIdx.x;   // over BHS_*16 float4s
  const int q = i >> 4, d4 = (i & 15) * 4;
  const float m0 = pm[q], m1 = pm[BHS_ + q];
  const float l0 = pl[q], l1 = pl[BHS_ + q];
  const float M = fmaxf(m0, m1);
  const float a0 = __builtin_amdgcn_exp2f(m0 - M);
  const float a1 = __builtin_amdgcn_exp2f(m1 - M);
  const float inv = 1.f / (l0 * a0 + l1 * a1);
  const float w0 = a0 * inv, w1 = a1 * inv;
  const float4 c0 = pctx[i];
  const float4 c1 = pctx[(size_t)BHS_ * 16 + i];
  bf16x4 o;
  o[0] = (bf16)(c0.x * w0 + c1.x * w1);
  o[1] = (bf16)(c0.y * w0 + c1.y * w1);
  o[2] = (bf16)(c0.z * w0 + c1.z * w1);
  o[3] = (bf16)(c0.w * w0 + c1.w * w1);
  const int bb = q >> 14, hh = (q >> 10) & (NH_ - 1), s = q & (S_ - 1);
  *(bf16x4*)(Ctx + ((size_t)(bb * S_ + s)) * H_ + hh * DH_ + d4) = o;
}

// ---------------- launcher ----------------------------------------------------
extern "C" void kernel_launch(void* const* d_in, const int* in_sizes, int n_in,
                              void* d_out, int out_size, void* d_ws, size_t ws_size,
                              hipStream_t stream) {
  (void)in_sizes; (void)n_in; (void)out_size; (void)ws_size;
  const float* x    = (const float*)d_in[0];
  const float* mask = (const float*)d_in[1];
  const float* wq   = (const float*)d_in[2];
  const float* bq   = (const float*)d_in[3];
  const float* wk   = (const float*)d_in[4];
  const float* bk   = (const float*)d_in[5];
  const float* wv   = (const float*)d_in[6];
  const float* bv   = (const float*)d_in[7];
  const float* wo   = (const float*)d_in[8];
  const float* bo   = (const float*)d_in[9];
  const float* aat  = (const float*)d_in[10];
  const float* wi   = (const float*)d_in[11];
  const float* bi   = (const float*)d_in[12];
  const float* wf   = (const float*)d_in[13];
  const float* bf_  = (const float*)d_in[14];
  const float* afn  = (const float*)d_in[15];

  char* ws = (char*)d_ws;
  size_t o = 0;
  bf16* WtQKV = (bf16*)(ws + o); o += (size_t)L_ * 3 * H_ * H_ * 2; // 24MB [L][3072][1024]
  bf16* WtO = (bf16*)(ws + o); o += (size_t)L_ * H_ * H_ * 2;       //  8MB
  bf16* WtI = (bf16*)(ws + o); o += (size_t)L_ * H_ * F_ * 2;       // 32MB
  bf16* WtF = (bf16*)(ws + o); o += (size_t)L_ * F_ * H_ * 2;       // 32MB
  bf16* madd = (bf16*)(ws + o); o += (size_t)B_ * S_ * S_ * 2;      //  4MB
  bf16* xb  = (bf16*)(ws + o); o += (size_t)M_ * H_ * 2;            //  4MB
  bf16* qb  = (bf16*)(ws + o); o += (size_t)M_ * H_ * 2;
  bf16* kbf = (bf16*)(ws + o); o += (size_t)M_ * H_ * 2;
  bf16* vt  = (bf16*)(ws + o); o += (size_t)M_ * H_ * 2;
  bf16* ctx = (bf16*)(ws + o); o += (size_t)M_ * H_ * 2;
  bf16* itm = (bf16*)(ws + o); o += (size_t)M_ * F_ * 2;            // 16MB
  float* part = (float*)(ws + o); o += (size_t)4 * M_ * H_ * 4;     // 32MB scratch region
  bf16* partb = (bf16*)part;                                        // bf16 view
  // attention partials overlay `part`: pctx | pm | pl (17.3MB)
  float* pctx = part;
  float* pm   = part + (size_t)2 * BHS_ * 64;
  float* pl   = pm + (size_t)2 * BHS_;

  float* xf = (float*)d_out;  // running x lives in d_out (fp32)

  const dim3 tb(32, 8);
  const size_t HH = (size_t)H_ * H_;
  transpose_cvt<<<dim3(H_/32, H_/32, L_), tb, 0, stream>>>(wq, WtQKV,          H_, H_, HH, 3*HH);
  transpose_cvt<<<dim3(H_/32, H_/32, L_), tb, 0, stream>>>(wk, WtQKV + HH,     H_, H_, HH, 3*HH);
  transpose_cvt<<<dim3(H_/32, H_/32, L_), tb, 0, stream>>>(wv, WtQKV + 2*HH,   H_, H_, HH, 3*HH);
  transpose_cvt<<<dim3(H_/32, H_/32, L_), tb, 0, stream>>>(wo, WtO, H_, H_, HH, HH);
  transpose_cvt<<<dim3(F_/32, H_/32, L_), tb, 0, stream>>>(wi, WtI, H_, F_, (size_t)H_*F_, (size_t)H_*F_);
  transpose_cvt<<<dim3(H_/32, F_/32, L_), tb, 0, stream>>>(wf, WtF, F_, H_, (size_t)F_*H_, (size_t)F_*H_);
  mask_cvt<<<dim3((B_*S_*S_/4)/256), 256, 0, stream>>>((const float4*)mask, (bf16x4*)madd);
  init_x_kernel<<<dim3((M_ * H_ / 4) / 256), 256, 0, stream>>>(
      (const float4*)x, (float4*)xf, (bf16x4*)xb);

  for (int l = 0; l < L_; ++l) {
    // QKV fused (N=3072), split-K=2, bf16 partials
    gemm128_kernel<4><<<dim3(24, M_/128, 2), 256, 0, stream>>>(
        xb, WtQKV + (size_t)l * 3 * HH, nullptr, partb, nullptr, nullptr,
        nullptr, 3072, H_, H_ / 2);
    qkv_combine<<<dim3((M_ * 3072 / 4) / 256), 256, 0, stream>>>(
        (const bf16x4*)partb, bq + l * H_, bk + l * H_, bv + l * H_, qb, kbf, vt);
    // attention (kv-split=2) + combine
    attn_kernel3<<<dim3(S_/64, NH_, B_*2), 256, 0, stream>>>(
        qb, kbf, vt, madd, pctx, pm, pl);
    attn_combine<<<dim3((BHS_ * 16) / 256), 256, 0, stream>>>(
        (const float4*)pctx, pm, pl, ctx);
    // O-proj: split-K=4, fp32 partials + residual reduce
    gemm128_kernel<3><<<dim3(H_/128, M_/128, 4), 256, 0, stream>>>(
        ctx, WtO + (size_t)l * HH, nullptr, nullptr, nullptr, nullptr,
        part, H_, H_, H_ / 4);
    reduce_residual<<<dim3((M_ * H_ / 4) / 256), 256, 0, stream>>>(
        (const float4*)part, bo + l * H_, aat + l, (float4*)xf, (bf16x4*)xb);
    // FFN1: split-K=2, bf16 partials + gelu combine
    gemm128_kernel<4><<<dim3(F_/128, M_/128, 2), 256, 0, stream>>>(
        xb, WtI + (size_t)l * H_ * F_, nullptr, partb, nullptr, nullptr,
        nullptr, F_, H_, H_ / 2);
    ffn1_combine<<<dim3((M_ * F_ / 4) / 256), 256, 0, stream>>>(
        (const bf16x4*)partb, bi + l * F_, (bf16x4*)itm);
    // FFN2: split-K=4, fp32 partials + residual reduce
    gemm128_kernel<3><<<dim3(H_/128, M_/128, 4), 256, 0, stream>>>(
        itm, WtF + (size_t)l * F_ * H_, nullptr, nullptr, nullptr, nullptr,
        part, H_, F_, F_ / 4);
    reduce_residual<<<dim3((M_ * H_ / 4) / 256), 256, 0, stream>>>(
        (const float4*)part, bf_ + l * H_, afn + l, (float4*)xf, (bf16x4*)xb);
  }
}

// Round 5
// 761.912 us; speedup vs baseline: 1.3295x; 1.3295x over previous
//
#include <hip/hip_runtime.h>
#include <cstdint>

#define B_  2
#define S_  1024
#define H_  1024
#define NH_ 16
#define DH_ 64
#define F_  4096
#define L_  4
#define M_  (B_*S_)        // 2048 rows in all GEMMs
#define BHS_ (B_*NH_*S_)   // 32768 (b,h,s) rows in attention

typedef __bf16 bf16;
typedef __bf16 bf16x8 __attribute__((ext_vector_type(8)));
typedef __bf16 bf16x4 __attribute__((ext_vector_type(4)));
typedef __bf16 bf16x2 __attribute__((ext_vector_type(2)));
typedef float  f32x4  __attribute__((ext_vector_type(4)));

// ---------------- async global->LDS (16B per lane), CK-style addrspace cast ----
__device__ __forceinline__ void async_ld16(void* lds, const void* g) {
  auto* lp = reinterpret_cast<__attribute__((address_space(3))) unsigned int*>(
      reinterpret_cast<uintptr_t>(lds));
  const auto* gp = reinterpret_cast<const __attribute__((address_space(1))) unsigned int*>(
      reinterpret_cast<uintptr_t>(g));
  __builtin_amdgcn_global_load_lds(gp, lp, 16, 0, 0);
}

__device__ __forceinline__ float gelu_tanh(float x) {
  float u = 0.7978845608028654f * (x + 0.044715f * x * x * x);
  u = fminf(fmaxf(u, -15.f), 15.f);
  float e = __builtin_amdgcn_exp2f(u * 2.8853900817779268f); // exp(2u)
  return 0.5f * x * (1.f + (e - 1.f) / (e + 1.f));
}

// ---------------- weight transpose + fp32->bf16 convert:  W[K][N] -> Wt[N][K] --
__global__ __launch_bounds__(256) void transpose_cvt(
    const float* __restrict__ src, bf16* __restrict__ dst, int K, int N,
    size_t src_z, size_t dst_z) {
  __shared__ float t[32][33];
  const int n0 = blockIdx.x * 32, k0 = blockIdx.y * 32;
  const size_t so = (size_t)blockIdx.z * src_z;
  const size_t dz = (size_t)blockIdx.z * dst_z;
  const int x = threadIdx.x, y = threadIdx.y;
  #pragma unroll
  for (int i = 0; i < 32; i += 8)
    t[y + i][x] = src[so + (size_t)(k0 + y + i) * N + n0 + x];
  __syncthreads();
  #pragma unroll
  for (int i = 0; i < 32; i += 8)
    dst[dz + (size_t)(n0 + y + i) * K + k0 + x] = (bf16)t[x][y + i];
}

// ---------------- mask -> bf16 additive adder in log2 domain ------------------
__global__ __launch_bounds__(256) void mask_cvt(
    const float4* __restrict__ m, bf16x4* __restrict__ out) {
  const int i = blockIdx.x * 256 + (int)threadIdx.x;
  const float c2 = -10000.f * 1.44269504088896f;
  float4 v = m[i];
  bf16x4 o;
  o[0] = (bf16)((1.f - v.x) * c2);
  o[1] = (bf16)((1.f - v.y) * c2);
  o[2] = (bf16)((1.f - v.z) * c2);
  o[3] = (bf16)((1.f - v.w) * c2);
  out[i] = o;
}

// ---------------- x init: copy fp32 x -> xf (running x, = d_out) + bf16 mirror -
__global__ __launch_bounds__(256) void init_x_kernel(
    const float4* __restrict__ x, float4* __restrict__ xf, bf16x4* __restrict__ xb) {
  int i = blockIdx.x * 256 + threadIdx.x;
  float4 v = x[i];
  xf[i] = v;
  bf16x4 b;
  b[0] = (bf16)v.x; b[1] = (bf16)v.y; b[2] = (bf16)v.z; b[3] = (bf16)v.w;
  xb[i] = b;
}

// ---------------- m97-structure GEMM core: C[128x128] = A[.][ld] @ Bt[.][ld]^T -
__device__ __forceinline__ void gemm_core(
    const bf16* __restrict__ A, const bf16* __restrict__ Bt, int ld, int kLen,
    int m0, int n0, bf16* As, bf16* Bs, f32x4 (&acc)[4][4]) {
  const int tid = (int)threadIdx.x;
  const int w = tid >> 6, l = tid & 63;
  const int lr = l & 15, lg = l >> 4;
  const int wm = w >> 1, wn = w & 1;
  const int srow = l >> 2;            // 0..15 (staging row within 16-row chunk)
  const int scol = (l & 3) * 8;       // element offset (8 bf16 = 16B)

  const bf16* ag = A  + (size_t)(m0 + w * 32 + srow) * ld + scol;
  const bf16* bg = Bt + (size_t)(n0 + w * 32 + srow) * ld + scol;
  bf16* asd = As + (w * 32) * 32;
  bf16* bsd = Bs + (w * 32) * 32;

  for (int k0 = 0; k0 < kLen; k0 += 32) {
    __syncthreads();                  // prior frag reads done before overwrite
    async_ld16(asd,            ag);
    async_ld16(asd + 16 * 32,  ag + (size_t)16 * ld);
    async_ld16(bsd,            bg);
    async_ld16(bsd + 16 * 32,  bg + (size_t)16 * ld);
    ag += 32; bg += 32;
    __syncthreads();                  // vmcnt(0) drain: LDS tiles ready
    bf16x8 af[4], bv[4];
    #pragma unroll
    for (int i = 0; i < 4; ++i)
      af[i] = *(const bf16x8*)(As + (wm * 64 + i * 16 + lr) * 32 + lg * 8);
    #pragma unroll
    for (int i = 0; i < 4; ++i)
      bv[i] = *(const bf16x8*)(Bs + (wn * 64 + i * 16 + lr) * 32 + lg * 8);
    #pragma unroll
    for (int i = 0; i < 4; ++i)
      #pragma unroll
      for (int j = 0; j < 4; ++j)
        acc[i][j] = __builtin_amdgcn_mfma_f32_16x16x32_bf16(af[i], bv[j], acc[i][j], 0, 0, 0);
  }
}

// MODE 0: out_bf16 = acc+bias | MODE 1: out_bf16 = gelu(acc+bias)
// MODE 2: xf += alpha*(acc+bias) (fp32, in-place) and xb = bf16(xf)
// MODE 3: fp32 partial (no bias) -> part[z*M*N + idx]
template <int MODE>
__global__ __launch_bounds__(256) void gemm128_kernel(
    const bf16* __restrict__ A, const bf16* __restrict__ Bt,
    const float* __restrict__ bias, bf16* __restrict__ outb,
    float* __restrict__ outf, const float* __restrict__ alphap,
    float* __restrict__ part, int N, int K, int kSlice) {
  __shared__ __align__(16) bf16 As[128 * 32];
  __shared__ __align__(16) bf16 Bs[128 * 32];
  const int m0 = blockIdx.y * 128, n0 = blockIdx.x * 128;
  const int z = blockIdx.z;
  const f32x4 z4 = {0.f, 0.f, 0.f, 0.f};
  f32x4 acc[4][4];
  #pragma unroll
  for (int i = 0; i < 4; ++i)
    #pragma unroll
    for (int j = 0; j < 4; ++j) acc[i][j] = z4;

  gemm_core(A + (size_t)z * kSlice, Bt + (size_t)z * kSlice, K, kSlice,
            m0, n0, As, Bs, acc);

  const int tid = (int)threadIdx.x;
  const int w = tid >> 6, l = tid & 63;
  const int lr = l & 15, lg = l >> 4;
  const int wm = w >> 1, wn = w & 1;
  float alpha = 0.f;
  if (MODE == 2) alpha = *alphap;
  const size_t pbase = (MODE == 3) ? (size_t)z * M_ * (size_t)N : 0;
  #pragma unroll
  for (int i = 0; i < 4; ++i) {
    const int row0 = m0 + wm * 64 + i * 16 + lg * 4;
    #pragma unroll
    for (int j = 0; j < 4; ++j) {
      const int col = n0 + wn * 64 + j * 16 + lr;
      const float bvx = (MODE == 3) ? 0.f : bias[col];
      #pragma unroll
      for (int r = 0; r < 4; ++r) {
        const size_t idx = (size_t)(row0 + r) * N + col;
        float v = acc[i][j][r] + bvx;
        if (MODE == 3) {
          part[pbase + idx] = v;
        } else if (MODE == 1) {
          outb[idx] = (bf16)gelu_tanh(v);
        } else if (MODE == 2) {
          float xn = outf[idx] + alpha * v;
          outf[idx] = xn;
          outb[idx] = (bf16)xn;
        } else {
          outb[idx] = (bf16)v;
        }
      }
    }
  }
}

// ---------------- split-K reduce + bias + ReZero residual (fp32 partials, z=4) -
__global__ __launch_bounds__(256) void reduce_residual(
    const float4* __restrict__ part, const float* __restrict__ bias,
    const float* __restrict__ alphap, float4* __restrict__ xf,
    bf16x4* __restrict__ xb) {
  const int i = blockIdx.x * 256 + (int)threadIdx.x;   // over M_*H_/4
  const int nper = M_ * H_ / 4;
  float4 s = part[i];
  #pragma unroll
  for (int zz = 1; zz < 4; ++zz) {
    float4 p = part[i + (size_t)zz * nper];
    s.x += p.x; s.y += p.y; s.z += p.z; s.w += p.w;
  }
  const int col = (i * 4) & (H_ - 1);
  const float4 b4 = *(const float4*)(bias + col);
  const float a = *alphap;
  float4 xv = xf[i];
  xv.x += a * (s.x + b4.x);
  xv.y += a * (s.y + b4.y);
  xv.z += a * (s.z + b4.z);
  xv.w += a * (s.w + b4.w);
  xf[i] = xv;
  bf16x4 bb;
  bb[0] = (bf16)xv.x; bb[1] = (bf16)xv.y; bb[2] = (bf16)xv.z; bb[3] = (bf16)xv.w;
  xb[i] = bb;
}

// QKV fused: grid.z selects {Q,K,V}. Q,K -> [B,S,H] bf16. V -> Vt[B,NH,DH,S].
__global__ __launch_bounds__(256) void gemm_qkv_kernel(
    const bf16* __restrict__ A,
    const bf16* __restrict__ WtQ, const bf16* __restrict__ WtK, const bf16* __restrict__ WtV,
    const float* __restrict__ bq, const float* __restrict__ bk, const float* __restrict__ bvv,
    bf16* __restrict__ qo, bf16* __restrict__ ko, bf16* __restrict__ vt) {
  __shared__ __align__(16) bf16 As[128 * 32];
  __shared__ __align__(16) bf16 Bs[128 * 32];
  const int z = blockIdx.z;
  const bf16* Bt = (z == 0) ? WtQ : (z == 1) ? WtK : WtV;
  const float* bias = (z == 0) ? bq : (z == 1) ? bk : bvv;
  const int m0 = blockIdx.y * 128, n0 = blockIdx.x * 128;
  const f32x4 z4 = {0.f, 0.f, 0.f, 0.f};
  f32x4 acc[4][4];
  #pragma unroll
  for (int i = 0; i < 4; ++i)
    #pragma unroll
    for (int j = 0; j < 4; ++j) acc[i][j] = z4;

  gemm_core(A, Bt, H_, H_, m0, n0, As, Bs, acc);

  const int tid = (int)threadIdx.x;
  const int w = tid >> 6, l = tid & 63;
  const int lr = l & 15, lg = l >> 4;
  const int wm = w >> 1, wn = w & 1;
  if (z < 2) {
    bf16* out = z ? ko : qo;
    #pragma unroll
    for (int i = 0; i < 4; ++i) {
      const int row0 = m0 + wm * 64 + i * 16 + lg * 4;
      #pragma unroll
      for (int j = 0; j < 4; ++j) {
        const int col = n0 + wn * 64 + j * 16 + lr;
        const float bvx = bias[col];
        #pragma unroll
        for (int r = 0; r < 4; ++r)
          out[(size_t)(row0 + r) * H_ + col] = (bf16)(acc[i][j][r] + bvx);
      }
    }
  } else {  // V transposed: Vt[((b*NH+h)*DH+d)*S + s], 4 consecutive s per lane
    #pragma unroll
    for (int i = 0; i < 4; ++i) {
      const int row0 = m0 + wm * 64 + i * 16 + lg * 4;
      const int bb = row0 >> 10, ss = row0 & (S_ - 1);
      #pragma unroll
      for (int j = 0; j < 4; ++j) {
        const int col = n0 + wn * 64 + j * 16 + lr;
        const float bvx = bias[col];
        const int hh = col >> 6, dd = col & 63;
        bf16x4 pk;
        #pragma unroll
        for (int r = 0; r < 4; ++r) pk[r] = (bf16)(acc[i][j][r] + bvx);
        *(bf16x4*)(vt + (((size_t)(bb * NH_ + hh) * DH_ + dd) << 10) + ss) = pk;
      }
    }
  }
}

// ---------------- flash attention v5: LDS-staged K/V, double-buffered ---------
// grid (S/64, NH, B*2), 256 thr = 4 waves. Swapped QK^T (lane-local softmax).
// K/V tiles (64kv x 64d = 8KB each) staged via global_load_lds with XOR swizzle
// (linear dest + inverse-swizzled source + swizzled read), double-buffered;
// one barrier per tile hides global latency under compute (T3-minimum).
__global__ __launch_bounds__(256) void attn_kernel5(
    const bf16* __restrict__ Q, const bf16* __restrict__ Kb,
    const bf16* __restrict__ Vt, const bf16* __restrict__ madd,
    float* __restrict__ pctx, float* __restrict__ pm, float* __restrict__ pl) {
  const int tid = (int)threadIdx.x;
  const int w = tid >> 6, l = tid & 63;
  const int lr = l & 15, lg = l >> 4;
  const int r7 = lr & 7;
  const int h = blockIdx.y;
  const int b = blockIdx.z >> 1, half = blockIdx.z & 1;
  const int q0 = blockIdx.x * 64 + w * 16;
  const int kvbase = half * (S_ / 2);

  __shared__ __align__(16) bf16 Kt[2][64 * 64];  // [buf][kv][d] swizzled
  __shared__ __align__(16) bf16 Vs[2][64 * 64];  // [buf][d][kv] swizzled
  __shared__ unsigned int Pu[4][16][36];         // per-wave P, u32-packed bf16

  const bf16* qp = Q + ((size_t)(b * S_ + q0 + lr)) * H_ + h * DH_;
  const bf16x8 qa0 = *(const bf16x8*)(qp + lg * 8);
  const bf16x8 qa1 = *(const bf16x8*)(qp + 32 + lg * 8);

  const f32x4 z4 = {0.f, 0.f, 0.f, 0.f};
  f32x4 acc[4];
  #pragma unroll
  for (int dt = 0; dt < 4; ++dt) acc[dt] = z4;
  float mrow = -1e30f, ssum = 0.f;

  const bf16* Kbase = Kb + ((size_t)b * S_) * H_ + h * DH_;
  const bf16* Vbase = Vt + ((size_t)(b * NH_ + h)) * DH_ * S_;
  const bf16* Mb = madd + ((size_t)(b * S_ + q0 + lr)) * S_;

  const float c1 = 0.125f * 1.44269504088896f;   // scale * log2(e)
  const float THR = 10.f;                        // defer-max headroom (base-2)

  // stage: wave w covers rows w*16..w*16+15 (2 instrs of 8 rows).
  // dest linear (lane*16B); source chunk pre-swizzled: cs = ((l&7)^(l>>3))*8.
  const int sub = l >> 3;
  const int cs  = ((l & 7) ^ sub) * 8;
  auto stage = [&](int buf, int kv) {
    #pragma unroll
    for (int j = 0; j < 2; ++j) {
      const int rbase = w * 16 + j * 8;
      async_ld16(&Kt[buf][rbase * 64],
                 Kbase + (size_t)(kv + rbase + sub) * H_ + cs);
      async_ld16(&Vs[buf][rbase * 64],
                 Vbase + (size_t)(rbase + sub) * S_ + kv + cs);
    }
  };

  stage(0, kvbase);
  __syncthreads();                    // vmcnt(0) drain: tile 0 ready
  int cur = 0;
  #pragma unroll 1
  for (int it = 0; it < 8; ++it) {
    const int kv0 = kvbase + it * 64;
    if (it < 7) stage(cur ^ 1, kv0 + 64);   // async prefetch next tile
    // --- K frags + mask from LDS/global (swizzled read) ---------------------
    const bf16* Kc = &Kt[cur][0];
    const bf16* Vc = &Vs[cur][0];
    bf16x8 kf0[4], kf1[4];
    bf16x4 mk[4];
    #pragma unroll
    for (int t = 0; t < 4; ++t) {
      kf0[t] = *(const bf16x8*)(Kc + (t * 16 + lr) * 64 + ((lg ^ r7) * 8));
      kf1[t] = *(const bf16x8*)(Kc + (t * 16 + lr) * 64 + (((4 + lg) ^ r7) * 8));
      mk[t] = *(const bf16x4*)(Mb + kv0 + t * 16 + lg * 4);
    }
    // --- QK^T swapped: st[t][r] = scores[kv=16t+4lg+r][q=lr] ----------------
    f32x4 st[4];
    __builtin_amdgcn_s_setprio(1);
    #pragma unroll
    for (int t = 0; t < 4; ++t) {
      f32x4 s = __builtin_amdgcn_mfma_f32_16x16x32_bf16(kf0[t], qa0, z4, 0, 0, 0);
      st[t] = __builtin_amdgcn_mfma_f32_16x16x32_bf16(kf1[t], qa1, s, 0, 0, 0);
    }
    __builtin_amdgcn_s_setprio(0);
    // --- scale + mask (base-2 domain), lane-local ---------------------------
    float sv[4][4];
    #pragma unroll
    for (int t = 0; t < 4; ++t)
      #pragma unroll
      for (int r = 0; r < 4; ++r)
        sv[t][r] = st[t][r] * c1 + (float)mk[t][r];
    // --- row max: 15 local fmax + 2 shuffles --------------------------------
    float nm = sv[0][0];
    #pragma unroll
    for (int t = 0; t < 4; ++t)
      #pragma unroll
      for (int r = 0; r < 4; ++r) nm = fmaxf(nm, sv[t][r]);
    nm = fmaxf(nm, __shfl_xor(nm, 16));
    nm = fmaxf(nm, __shfl_xor(nm, 32));
    // --- defer-max rescale --------------------------------------------------
    if (__any(nm > mrow + THR)) {
      float newm = fmaxf(mrow, nm);
      float f = __builtin_amdgcn_exp2f(mrow - newm);
      mrow = newm;
      ssum *= f;
      #pragma unroll
      for (int dt = 0; dt < 4; ++dt)
        #pragma unroll
        for (int r = 0; r < 4; ++r) acc[dt][r] *= f;
    }
    // --- P = 2^(sv - mrow); local sum + 2 shuffles --------------------------
    float p[4][4];
    float ps = 0.f;
    #pragma unroll
    for (int t = 0; t < 4; ++t)
      #pragma unroll
      for (int r = 0; r < 4; ++r) {
        p[t][r] = __builtin_amdgcn_exp2f(sv[t][r] - mrow);
        ps += p[t][r];
      }
    ps += __shfl_xor(ps, 16);
    ps += __shfl_xor(ps, 32);
    ssum += ps;
    // --- pack P to LDS as u32 bf16-pairs ------------------------------------
    #pragma unroll
    for (int t = 0; t < 4; ++t)
      #pragma unroll
      for (int hh = 0; hh < 2; ++hh) {
        union { bf16x2 v; unsigned int u; } pk;
        pk.v[0] = (bf16)p[t][2 * hh];
        pk.v[1] = (bf16)p[t][2 * hh + 1];
        Pu[w][lr][8 * t + 2 * lg + hh] = pk.u;
      }
    const bf16x8 pf0 = *(const bf16x8*)&Pu[w][lr][4 * lg];
    const bf16x8 pf1 = *(const bf16x8*)&Pu[w][lr][16 + 4 * lg];
    // --- PV transposed from LDS V (swizzled read) ---------------------------
    __builtin_amdgcn_s_setprio(1);
    #pragma unroll
    for (int dt = 0; dt < 4; ++dt) {
      bf16x8 vb0 = *(const bf16x8*)(Vc + (dt * 16 + lr) * 64 + ((lg ^ r7) * 8));
      acc[dt] = __builtin_amdgcn_mfma_f32_16x16x32_bf16(vb0, pf0, acc[dt], 0, 0, 0);
    }
    #pragma unroll
    for (int dt = 0; dt < 4; ++dt) {
      bf16x8 vb1 = *(const bf16x8*)(Vc + (dt * 16 + lr) * 64 + (((4 + lg) ^ r7) * 8));
      acc[dt] = __builtin_amdgcn_mfma_f32_16x16x32_bf16(vb1, pf1, acc[dt], 0, 0, 0);
    }
    __builtin_amdgcn_s_setprio(0);
    __syncthreads();                  // drains prefetch (next tile ready), frees cur
    cur ^= 1;
  }
  // --- write unnormalized partials (lane owns q-row = lr) -------------------
  const int gq = (b * NH_ + h) * S_ + q0 + lr;
  const size_t rowi = (size_t)half * BHS_ + gq;
  #pragma unroll
  for (int dt = 0; dt < 4; ++dt)
    *(f32x4*)(pctx + rowi * 64 + dt * 16 + lg * 4) = acc[dt];
  if (lg == 0) { pm[rowi] = mrow; pl[rowi] = ssum; }
}

// ---------------- combine the two kv-halves -> ctx bf16 ----------------------
__global__ __launch_bounds__(256) void attn_combine(
    const float4* __restrict__ pctx, const float* __restrict__ pm,
    const float* __restrict__ pl, bf16* __restrict__ Ctx) {
  const int i = blockIdx.x * 256 + (int)threadIdx.x;   // over BHS_*16 float4s
  const int q = i >> 4, d4 = (i & 15) * 4;
  const float m0 = pm[q], m1 = pm[BHS_ + q];
  const float l0 = pl[q], l1 = pl[BHS_ + q];
  const float M = fmaxf(m0, m1);
  const float a0 = __builtin_amdgcn_exp2f(m0 - M);
  const float a1 = __builtin_amdgcn_exp2f(m1 - M);
  const float inv = 1.f / (l0 * a0 + l1 * a1);
  const float w0 = a0 * inv, w1 = a1 * inv;
  const float4 c0 = pctx[i];
  const float4 c1 = pctx[(size_t)BHS_ * 16 + i];
  bf16x4 o;
  o[0] = (bf16)(c0.x * w0 + c1.x * w1);
  o[1] = (bf16)(c0.y * w0 + c1.y * w1);
  o[2] = (bf16)(c0.z * w0 + c1.z * w1);
  o[3] = (bf16)(c0.w * w0 + c1.w * w1);
  const int bb = q >> 14, hh = (q >> 10) & (NH_ - 1), s = q & (S_ - 1);
  *(bf16x4*)(Ctx + ((size_t)(bb * S_ + s)) * H_ + hh * DH_ + d4) = o;
}

// ---------------- launcher ----------------------------------------------------
extern "C" void kernel_launch(void* const* d_in, const int* in_sizes, int n_in,
                              void* d_out, int out_size, void* d_ws, size_t ws_size,
                              hipStream_t stream) {
  (void)in_sizes; (void)n_in; (void)out_size; (void)ws_size;
  const float* x    = (const float*)d_in[0];
  const float* mask = (const float*)d_in[1];
  const float* wq   = (const float*)d_in[2];
  const float* bq   = (const float*)d_in[3];
  const float* wk   = (const float*)d_in[4];
  const float* bk   = (const float*)d_in[5];
  const float* wv   = (const float*)d_in[6];
  const float* bv   = (const float*)d_in[7];
  const float* wo   = (const float*)d_in[8];
  const float* bo   = (const float*)d_in[9];
  const float* aat  = (const float*)d_in[10];
  const float* wi   = (const float*)d_in[11];
  const float* bi   = (const float*)d_in[12];
  const float* wf   = (const float*)d_in[13];
  const float* bf_  = (const float*)d_in[14];
  const float* afn  = (const float*)d_in[15];

  char* ws = (char*)d_ws;
  size_t o = 0;
  bf16* WtQKV = (bf16*)(ws + o); o += (size_t)L_ * 3 * H_ * H_ * 2; // 24MB [L][3][1024][1024]
  bf16* WtO = (bf16*)(ws + o); o += (size_t)L_ * H_ * H_ * 2;       //  8MB
  bf16* WtI = (bf16*)(ws + o); o += (size_t)L_ * H_ * F_ * 2;       // 32MB
  bf16* WtF = (bf16*)(ws + o); o += (size_t)L_ * F_ * H_ * 2;       // 32MB
  bf16* madd = (bf16*)(ws + o); o += (size_t)B_ * S_ * S_ * 2;      //  4MB
  bf16* xb  = (bf16*)(ws + o); o += (size_t)M_ * H_ * 2;            //  4MB
  bf16* qb  = (bf16*)(ws + o); o += (size_t)M_ * H_ * 2;
  bf16* kbf = (bf16*)(ws + o); o += (size_t)M_ * H_ * 2;
  bf16* vt  = (bf16*)(ws + o); o += (size_t)M_ * H_ * 2;
  bf16* ctx = (bf16*)(ws + o); o += (size_t)M_ * H_ * 2;
  bf16* itm = (bf16*)(ws + o); o += (size_t)M_ * F_ * 2;            // 16MB
  float* part = (float*)(ws + o); o += (size_t)4 * M_ * H_ * 4;     // 32MB (168MB total)
  // attention partials overlay `part`: pctx | pm | pl (17.3MB)
  float* pctx = part;
  float* pm   = part + (size_t)2 * BHS_ * 64;
  float* pl   = pm + (size_t)2 * BHS_;

  float* xf = (float*)d_out;  // running x lives in d_out (fp32)

  const dim3 tb(32, 8);
  const size_t HH = (size_t)H_ * H_;
  transpose_cvt<<<dim3(H_/32, H_/32, L_), tb, 0, stream>>>(wq, WtQKV,        H_, H_, HH, 3*HH);
  transpose_cvt<<<dim3(H_/32, H_/32, L_), tb, 0, stream>>>(wk, WtQKV + HH,   H_, H_, HH, 3*HH);
  transpose_cvt<<<dim3(H_/32, H_/32, L_), tb, 0, stream>>>(wv, WtQKV + 2*HH, H_, H_, HH, 3*HH);
  transpose_cvt<<<dim3(H_/32, H_/32, L_), tb, 0, stream>>>(wo, WtO, H_, H_, HH, HH);
  transpose_cvt<<<dim3(F_/32, H_/32, L_), tb, 0, stream>>>(wi, WtI, H_, F_, (size_t)H_*F_, (size_t)H_*F_);
  transpose_cvt<<<dim3(H_/32, F_/32, L_), tb, 0, stream>>>(wf, WtF, F_, H_, (size_t)F_*H_, (size_t)F_*H_);
  mask_cvt<<<dim3((B_*S_*S_/4)/256), 256, 0, stream>>>((const float4*)mask, (bf16x4*)madd);
  init_x_kernel<<<dim3((M_ * H_ / 4) / 256), 256, 0, stream>>>(
      (const float4*)x, (float4*)xf, (bf16x4*)xb);

  for (int l = 0; l < L_; ++l) {
    // QKV fused (grid.z = 3), direct outputs (round-3 proven path)
    gemm_qkv_kernel<<<dim3(H_/128, M_/128, 3), 256, 0, stream>>>(
        xb, WtQKV + (size_t)l * 3 * HH, WtQKV + (size_t)l * 3 * HH + HH,
        WtQKV + (size_t)l * 3 * HH + 2 * HH,
        bq + l * H_, bk + l * H_, bv + l * H_, qb, kbf, vt);
    // attention (kv-split=2, LDS-staged) + combine
    attn_kernel5<<<dim3(S_/64, NH_, B_*2), 256, 0, stream>>>(
        qb, kbf, vt, madd, pctx, pm, pl);
    attn_combine<<<dim3((BHS_ * 16) / 256), 256, 0, stream>>>(
        (const float4*)pctx, pm, pl, ctx);
    // O-proj: split-K=4, fp32 partials + residual reduce
    gemm128_kernel<3><<<dim3(H_/128, M_/128, 4), 256, 0, stream>>>(
        ctx, WtO + (size_t)l * HH, nullptr, nullptr, nullptr, nullptr,
        part, H_, H_, H_ / 4);
    reduce_residual<<<dim3((M_ * H_ / 4) / 256), 256, 0, stream>>>(
        (const float4*)part, bo + l * H_, aat + l, (float4*)xf, (bf16x4*)xb);
    // FFN1: direct gelu output (round-3 proven path)
    gemm128_kernel<1><<<dim3(F_/128, M_/128), 256, 0, stream>>>(
        xb, WtI + (size_t)l * H_ * F_, bi + l * F_, itm, nullptr, nullptr,
        nullptr, F_, H_, H_);
    // FFN2: split-K=4, fp32 partials + residual reduce
    gemm128_kernel<3><<<dim3(H_/128, M_/128, 4), 256, 0, stream>>>(
        itm, WtF + (size_t)l * F_ * H_, nullptr, nullptr, nullptr, nullptr,
        part, H_, F_, F_ / 4);
    reduce_residual<<<dim3((M_ * H_ / 4) / 256), 256, 0, stream>>>(
        (const float4*)part, bf_ + l * H_, afn + l, (float4*)xf, (bf16x4*)xb);
  }
}

// Round 6
// 679.097 us; speedup vs baseline: 1.4917x; 1.1219x over previous
//
#include <hip/hip_runtime.h>
#include <cstdint>

#define B_  2
#define S_  1024
#define H_  1024
#define NH_ 16
#define DH_ 64
#define F_  4096
#define L_  4
#define M_  (B_*S_)        // 2048 rows in all GEMMs
#define BHS_ (B_*NH_*S_)   // 32768 (b,h,s) rows in attention

typedef __bf16 bf16;
typedef __bf16 bf16x8 __attribute__((ext_vector_type(8)));
typedef __bf16 bf16x4 __attribute__((ext_vector_type(4)));
typedef __bf16 bf16x2 __attribute__((ext_vector_type(2)));
typedef float  f32x4  __attribute__((ext_vector_type(4)));

// ---------------- async global->LDS (16B per lane), CK-style addrspace cast ----
__device__ __forceinline__ void async_ld16(void* lds, const void* g) {
  auto* lp = reinterpret_cast<__attribute__((address_space(3))) unsigned int*>(
      reinterpret_cast<uintptr_t>(lds));
  const auto* gp = reinterpret_cast<const __attribute__((address_space(1))) unsigned int*>(
      reinterpret_cast<uintptr_t>(g));
  __builtin_amdgcn_global_load_lds(gp, lp, 16, 0, 0);
}

__device__ __forceinline__ float gelu_tanh(float x) {
  float u = 0.7978845608028654f * (x + 0.044715f * x * x * x);
  u = fminf(fmaxf(u, -15.f), 15.f);
  float e = __builtin_amdgcn_exp2f(u * 2.8853900817779268f); // exp(2u)
  return 0.5f * x * (1.f + (e - 1.f) / (e + 1.f));
}

// ---------------- weight transpose + fp32->bf16 convert:  W[K][N] -> Wt[N][K] --
__global__ __launch_bounds__(256) void transpose_cvt(
    const float* __restrict__ src, bf16* __restrict__ dst, int K, int N,
    size_t src_z, size_t dst_z) {
  __shared__ float t[32][33];
  const int n0 = blockIdx.x * 32, k0 = blockIdx.y * 32;
  const size_t so = (size_t)blockIdx.z * src_z;
  const size_t dz = (size_t)blockIdx.z * dst_z;
  const int x = threadIdx.x, y = threadIdx.y;
  #pragma unroll
  for (int i = 0; i < 32; i += 8)
    t[y + i][x] = src[so + (size_t)(k0 + y + i) * N + n0 + x];
  __syncthreads();
  #pragma unroll
  for (int i = 0; i < 32; i += 8)
    dst[dz + (size_t)(n0 + y + i) * K + k0 + x] = (bf16)t[x][y + i];
}

// ---------------- mask -> bf16 additive adder in log2 domain ------------------
__global__ __launch_bounds__(256) void mask_cvt(
    const float4* __restrict__ m, bf16x4* __restrict__ out) {
  const int i = blockIdx.x * 256 + (int)threadIdx.x;
  const float c2 = -10000.f * 1.44269504088896f;
  float4 v = m[i];
  bf16x4 o;
  o[0] = (bf16)((1.f - v.x) * c2);
  o[1] = (bf16)((1.f - v.y) * c2);
  o[2] = (bf16)((1.f - v.z) * c2);
  o[3] = (bf16)((1.f - v.w) * c2);
  out[i] = o;
}

// ---------------- x init: copy fp32 x -> xf (running x, = d_out) + bf16 mirror -
__global__ __launch_bounds__(256) void init_x_kernel(
    const float4* __restrict__ x, float4* __restrict__ xf, bf16x4* __restrict__ xb) {
  int i = blockIdx.x * 256 + threadIdx.x;
  float4 v = x[i];
  xf[i] = v;
  bf16x4 b;
  b[0] = (bf16)v.x; b[1] = (bf16)v.y; b[2] = (bf16)v.z; b[3] = (bf16)v.w;
  xb[i] = b;
}

// ---------------- double-buffered GEMM core: C[128x128] = A[.][ld] @ Bt[.][ld]^T
// T3-minimum schedule (proven in attn_kernel5): STAGE(next) issued BEFORE
// compute(cur); the compiler's vmcnt(0)-drain at the end-of-iter barrier then
// lands AFTER the 16 MFMA, hiding staging latency under compute.
// As/Bs are [2][128][32] (16KB each, 32KB total).
__device__ __forceinline__ void gemm_core(
    const bf16* __restrict__ A, const bf16* __restrict__ Bt, int ld, int kLen,
    int m0, int n0, bf16* As, bf16* Bs, f32x4 (&acc)[4][4]) {
  const int tid = (int)threadIdx.x;
  const int w = tid >> 6, l = tid & 63;
  const int lr = l & 15, lg = l >> 4;
  const int wm = w >> 1, wn = w & 1;
  const int srow = l >> 2;            // 0..15 (staging row within 16-row chunk)
  const int scol = (l & 3) * 8;       // element offset (8 bf16 = 16B)

  const bf16* ag = A  + (size_t)(m0 + w * 32 + srow) * ld + scol;
  const bf16* bg = Bt + (size_t)(n0 + w * 32 + srow) * ld + scol;
  const int soff = (w * 32) * 32;

  auto stage = [&](int buf, int kk) {
    bf16* ad = As + buf * 4096 + soff;
    bf16* bd = Bs + buf * 4096 + soff;
    async_ld16(ad,           ag + kk);
    async_ld16(ad + 16 * 32, ag + kk + (size_t)16 * ld);
    async_ld16(bd,           bg + kk);
    async_ld16(bd + 16 * 32, bg + kk + (size_t)16 * ld);
  };

  stage(0, 0);
  __syncthreads();                    // vmcnt(0) drain: tile 0 ready
  int cur = 0;
  for (int k0 = 0; k0 < kLen; k0 += 32) {
    if (k0 + 32 < kLen) stage(cur ^ 1, k0 + 32);   // async prefetch next tile
    const bf16* Ab = As + cur * 4096;
    const bf16* Bb = Bs + cur * 4096;
    bf16x8 af[4], bv[4];
    #pragma unroll
    for (int i = 0; i < 4; ++i)
      af[i] = *(const bf16x8*)(Ab + (wm * 64 + i * 16 + lr) * 32 + lg * 8);
    #pragma unroll
    for (int i = 0; i < 4; ++i)
      bv[i] = *(const bf16x8*)(Bb + (wn * 64 + i * 16 + lr) * 32 + lg * 8);
    #pragma unroll
    for (int i = 0; i < 4; ++i)
      #pragma unroll
      for (int j = 0; j < 4; ++j)
        acc[i][j] = __builtin_amdgcn_mfma_f32_16x16x32_bf16(af[i], bv[j], acc[i][j], 0, 0, 0);
    __syncthreads();                  // drains prefetch (next tile ready), frees cur
    cur ^= 1;
  }
}

// MODE 0: out_bf16 = acc+bias | MODE 1: out_bf16 = gelu(acc+bias)
// MODE 2: xf += alpha*(acc+bias) (fp32, in-place) and xb = bf16(xf)
// MODE 3: fp32 partial (no bias) -> part[z*M*N + idx]
template <int MODE>
__global__ __launch_bounds__(256) void gemm128_kernel(
    const bf16* __restrict__ A, const bf16* __restrict__ Bt,
    const float* __restrict__ bias, bf16* __restrict__ outb,
    float* __restrict__ outf, const float* __restrict__ alphap,
    float* __restrict__ part, int N, int K, int kSlice) {
  __shared__ __align__(16) bf16 As[2 * 128 * 32];
  __shared__ __align__(16) bf16 Bs[2 * 128 * 32];
  const int m0 = blockIdx.y * 128, n0 = blockIdx.x * 128;
  const int z = blockIdx.z;
  const f32x4 z4 = {0.f, 0.f, 0.f, 0.f};
  f32x4 acc[4][4];
  #pragma unroll
  for (int i = 0; i < 4; ++i)
    #pragma unroll
    for (int j = 0; j < 4; ++j) acc[i][j] = z4;

  gemm_core(A + (size_t)z * kSlice, Bt + (size_t)z * kSlice, K, kSlice,
            m0, n0, As, Bs, acc);

  const int tid = (int)threadIdx.x;
  const int w = tid >> 6, l = tid & 63;
  const int lr = l & 15, lg = l >> 4;
  const int wm = w >> 1, wn = w & 1;
  float alpha = 0.f;
  if (MODE == 2) alpha = *alphap;
  const size_t pbase = (MODE == 3) ? (size_t)z * M_ * (size_t)N : 0;
  #pragma unroll
  for (int i = 0; i < 4; ++i) {
    const int row0 = m0 + wm * 64 + i * 16 + lg * 4;
    #pragma unroll
    for (int j = 0; j < 4; ++j) {
      const int col = n0 + wn * 64 + j * 16 + lr;
      const float bvx = (MODE == 3) ? 0.f : bias[col];
      #pragma unroll
      for (int r = 0; r < 4; ++r) {
        const size_t idx = (size_t)(row0 + r) * N + col;
        float v = acc[i][j][r] + bvx;
        if (MODE == 3) {
          part[pbase + idx] = v;
        } else if (MODE == 1) {
          outb[idx] = (bf16)gelu_tanh(v);
        } else if (MODE == 2) {
          float xn = outf[idx] + alpha * v;
          outf[idx] = xn;
          outb[idx] = (bf16)xn;
        } else {
          outb[idx] = (bf16)v;
        }
      }
    }
  }
}

// ---------------- split-K reduce + bias + ReZero residual (fp32 partials, z=4) -
__global__ __launch_bounds__(256) void reduce_residual(
    const float4* __restrict__ part, const float* __restrict__ bias,
    const float* __restrict__ alphap, float4* __restrict__ xf,
    bf16x4* __restrict__ xb) {
  const int i = blockIdx.x * 256 + (int)threadIdx.x;   // over M_*H_/4
  const int nper = M_ * H_ / 4;
  float4 s = part[i];
  #pragma unroll
  for (int zz = 1; zz < 4; ++zz) {
    float4 p = part[i + (size_t)zz * nper];
    s.x += p.x; s.y += p.y; s.z += p.z; s.w += p.w;
  }
  const int col = (i * 4) & (H_ - 1);
  const float4 b4 = *(const float4*)(bias + col);
  const float a = *alphap;
  float4 xv = xf[i];
  xv.x += a * (s.x + b4.x);
  xv.y += a * (s.y + b4.y);
  xv.z += a * (s.z + b4.z);
  xv.w += a * (s.w + b4.w);
  xf[i] = xv;
  bf16x4 bb;
  bb[0] = (bf16)xv.x; bb[1] = (bf16)xv.y; bb[2] = (bf16)xv.z; bb[3] = (bf16)xv.w;
  xb[i] = bb;
}

// QKV fused: grid.z selects {Q,K,V}. Q,K -> [B,S,H] bf16. V -> Vt[B,NH,DH,S].
__global__ __launch_bounds__(256) void gemm_qkv_kernel(
    const bf16* __restrict__ A,
    const bf16* __restrict__ WtQ, const bf16* __restrict__ WtK, const bf16* __restrict__ WtV,
    const float* __restrict__ bq, const float* __restrict__ bk, const float* __restrict__ bvv,
    bf16* __restrict__ qo, bf16* __restrict__ ko, bf16* __restrict__ vt) {
  __shared__ __align__(16) bf16 As[2 * 128 * 32];
  __shared__ __align__(16) bf16 Bs[2 * 128 * 32];
  const int z = blockIdx.z;
  const bf16* Bt = (z == 0) ? WtQ : (z == 1) ? WtK : WtV;
  const float* bias = (z == 0) ? bq : (z == 1) ? bk : bvv;
  const int m0 = blockIdx.y * 128, n0 = blockIdx.x * 128;
  const f32x4 z4 = {0.f, 0.f, 0.f, 0.f};
  f32x4 acc[4][4];
  #pragma unroll
  for (int i = 0; i < 4; ++i)
    #pragma unroll
    for (int j = 0; j < 4; ++j) acc[i][j] = z4;

  gemm_core(A, Bt, H_, H_, m0, n0, As, Bs, acc);

  const int tid = (int)threadIdx.x;
  const int w = tid >> 6, l = tid & 63;
  const int lr = l & 15, lg = l >> 4;
  const int wm = w >> 1, wn = w & 1;
  if (z < 2) {
    bf16* out = z ? ko : qo;
    #pragma unroll
    for (int i = 0; i < 4; ++i) {
      const int row0 = m0 + wm * 64 + i * 16 + lg * 4;
      #pragma unroll
      for (int j = 0; j < 4; ++j) {
        const int col = n0 + wn * 64 + j * 16 + lr;
        const float bvx = bias[col];
        #pragma unroll
        for (int r = 0; r < 4; ++r)
          out[(size_t)(row0 + r) * H_ + col] = (bf16)(acc[i][j][r] + bvx);
      }
    }
  } else {  // V transposed: Vt[((b*NH+h)*DH+d)*S + s], 4 consecutive s per lane
    #pragma unroll
    for (int i = 0; i < 4; ++i) {
      const int row0 = m0 + wm * 64 + i * 16 + lg * 4;
      const int bb = row0 >> 10, ss = row0 & (S_ - 1);
      #pragma unroll
      for (int j = 0; j < 4; ++j) {
        const int col = n0 + wn * 64 + j * 16 + lr;
        const float bvx = bias[col];
        const int hh = col >> 6, dd = col & 63;
        bf16x4 pk;
        #pragma unroll
        for (int r = 0; r < 4; ++r) pk[r] = (bf16)(acc[i][j][r] + bvx);
        *(bf16x4*)(vt + (((size_t)(bb * NH_ + hh) * DH_ + dd) << 10) + ss) = pk;
      }
    }
  }
}

// ---------------- flash attention v5: LDS-staged K/V, double-buffered ---------
// grid (S/64, NH, B*2), 256 thr = 4 waves. Swapped QK^T (lane-local softmax).
__global__ __launch_bounds__(256) void attn_kernel5(
    const bf16* __restrict__ Q, const bf16* __restrict__ Kb,
    const bf16* __restrict__ Vt, const bf16* __restrict__ madd,
    float* __restrict__ pctx, float* __restrict__ pm, float* __restrict__ pl) {
  const int tid = (int)threadIdx.x;
  const int w = tid >> 6, l = tid & 63;
  const int lr = l & 15, lg = l >> 4;
  const int r7 = lr & 7;
  const int h = blockIdx.y;
  const int b = blockIdx.z >> 1, half = blockIdx.z & 1;
  const int q0 = blockIdx.x * 64 + w * 16;
  const int kvbase = half * (S_ / 2);

  __shared__ __align__(16) bf16 Kt[2][64 * 64];  // [buf][kv][d] swizzled
  __shared__ __align__(16) bf16 Vs[2][64 * 64];  // [buf][d][kv] swizzled
  __shared__ unsigned int Pu[4][16][36];         // per-wave P, u32-packed bf16

  const bf16* qp = Q + ((size_t)(b * S_ + q0 + lr)) * H_ + h * DH_;
  const bf16x8 qa0 = *(const bf16x8*)(qp + lg * 8);
  const bf16x8 qa1 = *(const bf16x8*)(qp + 32 + lg * 8);

  const f32x4 z4 = {0.f, 0.f, 0.f, 0.f};
  f32x4 acc[4];
  #pragma unroll
  for (int dt = 0; dt < 4; ++dt) acc[dt] = z4;
  float mrow = -1e30f, ssum = 0.f;

  const bf16* Kbase = Kb + ((size_t)b * S_) * H_ + h * DH_;
  const bf16* Vbase = Vt + ((size_t)(b * NH_ + h)) * DH_ * S_;
  const bf16* Mb = madd + ((size_t)(b * S_ + q0 + lr)) * S_;

  const float c1 = 0.125f * 1.44269504088896f;   // scale * log2(e)
  const float THR = 10.f;                        // defer-max headroom (base-2)

  const int sub = l >> 3;
  const int cs  = ((l & 7) ^ sub) * 8;
  auto stage = [&](int buf, int kv) {
    #pragma unroll
    for (int j = 0; j < 2; ++j) {
      const int rbase = w * 16 + j * 8;
      async_ld16(&Kt[buf][rbase * 64],
                 Kbase + (size_t)(kv + rbase + sub) * H_ + cs);
      async_ld16(&Vs[buf][rbase * 64],
                 Vbase + (size_t)(rbase + sub) * S_ + kv + cs);
    }
  };

  stage(0, kvbase);
  __syncthreads();                    // vmcnt(0) drain: tile 0 ready
  int cur = 0;
  #pragma unroll 1
  for (int it = 0; it < 8; ++it) {
    const int kv0 = kvbase + it * 64;
    if (it < 7) stage(cur ^ 1, kv0 + 64);   // async prefetch next tile
    const bf16* Kc = &Kt[cur][0];
    const bf16* Vc = &Vs[cur][0];
    bf16x8 kf0[4], kf1[4];
    bf16x4 mk[4];
    #pragma unroll
    for (int t = 0; t < 4; ++t) {
      kf0[t] = *(const bf16x8*)(Kc + (t * 16 + lr) * 64 + ((lg ^ r7) * 8));
      kf1[t] = *(const bf16x8*)(Kc + (t * 16 + lr) * 64 + (((4 + lg) ^ r7) * 8));
      mk[t] = *(const bf16x4*)(Mb + kv0 + t * 16 + lg * 4);
    }
    f32x4 st[4];
    __builtin_amdgcn_s_setprio(1);
    #pragma unroll
    for (int t = 0; t < 4; ++t) {
      f32x4 s = __builtin_amdgcn_mfma_f32_16x16x32_bf16(kf0[t], qa0, z4, 0, 0, 0);
      st[t] = __builtin_amdgcn_mfma_f32_16x16x32_bf16(kf1[t], qa1, s, 0, 0, 0);
    }
    __builtin_amdgcn_s_setprio(0);
    float sv[4][4];
    #pragma unroll
    for (int t = 0; t < 4; ++t)
      #pragma unroll
      for (int r = 0; r < 4; ++r)
        sv[t][r] = st[t][r] * c1 + (float)mk[t][r];
    float nm = sv[0][0];
    #pragma unroll
    for (int t = 0; t < 4; ++t)
      #pragma unroll
      for (int r = 0; r < 4; ++r) nm = fmaxf(nm, sv[t][r]);
    nm = fmaxf(nm, __shfl_xor(nm, 16));
    nm = fmaxf(nm, __shfl_xor(nm, 32));
    if (__any(nm > mrow + THR)) {
      float newm = fmaxf(mrow, nm);
      float f = __builtin_amdgcn_exp2f(mrow - newm);
      mrow = newm;
      ssum *= f;
      #pragma unroll
      for (int dt = 0; dt < 4; ++dt)
        #pragma unroll
        for (int r = 0; r < 4; ++r) acc[dt][r] *= f;
    }
    float p[4][4];
    float ps = 0.f;
    #pragma unroll
    for (int t = 0; t < 4; ++t)
      #pragma unroll
      for (int r = 0; r < 4; ++r) {
        p[t][r] = __builtin_amdgcn_exp2f(sv[t][r] - mrow);
        ps += p[t][r];
      }
    ps += __shfl_xor(ps, 16);
    ps += __shfl_xor(ps, 32);
    ssum += ps;
    #pragma unroll
    for (int t = 0; t < 4; ++t)
      #pragma unroll
      for (int hh = 0; hh < 2; ++hh) {
        union { bf16x2 v; unsigned int u; } pk;
        pk.v[0] = (bf16)p[t][2 * hh];
        pk.v[1] = (bf16)p[t][2 * hh + 1];
        Pu[w][lr][8 * t + 2 * lg + hh] = pk.u;
      }
    const bf16x8 pf0 = *(const bf16x8*)&Pu[w][lr][4 * lg];
    const bf16x8 pf1 = *(const bf16x8*)&Pu[w][lr][16 + 4 * lg];
    __builtin_amdgcn_s_setprio(1);
    #pragma unroll
    for (int dt = 0; dt < 4; ++dt) {
      bf16x8 vb0 = *(const bf16x8*)(Vc + (dt * 16 + lr) * 64 + ((lg ^ r7) * 8));
      acc[dt] = __builtin_amdgcn_mfma_f32_16x16x32_bf16(vb0, pf0, acc[dt], 0, 0, 0);
    }
    #pragma unroll
    for (int dt = 0; dt < 4; ++dt) {
      bf16x8 vb1 = *(const bf16x8*)(Vc + (dt * 16 + lr) * 64 + (((4 + lg) ^ r7) * 8));
      acc[dt] = __builtin_amdgcn_mfma_f32_16x16x32_bf16(vb1, pf1, acc[dt], 0, 0, 0);
    }
    __builtin_amdgcn_s_setprio(0);
    __syncthreads();                  // drains prefetch (next tile ready), frees cur
    cur ^= 1;
  }
  const int gq = (b * NH_ + h) * S_ + q0 + lr;
  const size_t rowi = (size_t)half * BHS_ + gq;
  #pragma unroll
  for (int dt = 0; dt < 4; ++dt)
    *(f32x4*)(pctx + rowi * 64 + dt * 16 + lg * 4) = acc[dt];
  if (lg == 0) { pm[rowi] = mrow; pl[rowi] = ssum; }
}

// ---------------- combine the two kv-halves -> ctx bf16 ----------------------
__global__ __launch_bounds__(256) void attn_combine(
    const float4* __restrict__ pctx, const float* __restrict__ pm,
    const float* __restrict__ pl, bf16* __restrict__ Ctx) {
  const int i = blockIdx.x * 256 + (int)threadIdx.x;   // over BHS_*16 float4s
  const int q = i >> 4, d4 = (i & 15) * 4;
  const float m0 = pm[q], m1 = pm[BHS_ + q];
  const float l0 = pl[q], l1 = pl[BHS_ + q];
  const float M = fmaxf(m0, m1);
  const float a0 = __builtin_amdgcn_exp2f(m0 - M);
  const float a1 = __builtin_amdgcn_exp2f(m1 - M);
  const float inv = 1.f / (l0 * a0 + l1 * a1);
  const float w0 = a0 * inv, w1 = a1 * inv;
  const float4 c0 = pctx[i];
  const float4 c1 = pctx[(size_t)BHS_ * 16 + i];
  bf16x4 o;
  o[0] = (bf16)(c0.x * w0 + c1.x * w1);
  o[1] = (bf16)(c0.y * w0 + c1.y * w1);
  o[2] = (bf16)(c0.z * w0 + c1.z * w1);
  o[3] = (bf16)(c0.w * w0 + c1.w * w1);
  const int bb = q >> 14, hh = (q >> 10) & (NH_ - 1), s = q & (S_ - 1);
  *(bf16x4*)(Ctx + ((size_t)(bb * S_ + s)) * H_ + hh * DH_ + d4) = o;
}

// ---------------- launcher ----------------------------------------------------
extern "C" void kernel_launch(void* const* d_in, const int* in_sizes, int n_in,
                              void* d_out, int out_size, void* d_ws, size_t ws_size,
                              hipStream_t stream) {
  (void)in_sizes; (void)n_in; (void)out_size; (void)ws_size;
  const float* x    = (const float*)d_in[0];
  const float* mask = (const float*)d_in[1];
  const float* wq   = (const float*)d_in[2];
  const float* bq   = (const float*)d_in[3];
  const float* wk   = (const float*)d_in[4];
  const float* bk   = (const float*)d_in[5];
  const float* wv   = (const float*)d_in[6];
  const float* bv   = (const float*)d_in[7];
  const float* wo   = (const float*)d_in[8];
  const float* bo   = (const float*)d_in[9];
  const float* aat  = (const float*)d_in[10];
  const float* wi   = (const float*)d_in[11];
  const float* bi   = (const float*)d_in[12];
  const float* wf   = (const float*)d_in[13];
  const float* bf_  = (const float*)d_in[14];
  const float* afn  = (const float*)d_in[15];

  char* ws = (char*)d_ws;
  size_t o = 0;
  bf16* WtQKV = (bf16*)(ws + o); o += (size_t)L_ * 3 * H_ * H_ * 2; // 24MB [L][3][1024][1024]
  bf16* WtO = (bf16*)(ws + o); o += (size_t)L_ * H_ * H_ * 2;       //  8MB
  bf16* WtI = (bf16*)(ws + o); o += (size_t)L_ * H_ * F_ * 2;       // 32MB
  bf16* WtF = (bf16*)(ws + o); o += (size_t)L_ * F_ * H_ * 2;       // 32MB
  bf16* madd = (bf16*)(ws + o); o += (size_t)B_ * S_ * S_ * 2;      //  4MB
  bf16* xb  = (bf16*)(ws + o); o += (size_t)M_ * H_ * 2;            //  4MB
  bf16* qb  = (bf16*)(ws + o); o += (size_t)M_ * H_ * 2;
  bf16* kbf = (bf16*)(ws + o); o += (size_t)M_ * H_ * 2;
  bf16* vt  = (bf16*)(ws + o); o += (size_t)M_ * H_ * 2;
  bf16* ctx = (bf16*)(ws + o); o += (size_t)M_ * H_ * 2;
  bf16* itm = (bf16*)(ws + o); o += (size_t)M_ * F_ * 2;            // 16MB
  float* part = (float*)(ws + o); o += (size_t)4 * M_ * H_ * 4;     // 32MB (168MB total)
  // attention partials overlay `part`: pctx | pm | pl (17.3MB)
  float* pctx = part;
  float* pm   = part + (size_t)2 * BHS_ * 64;
  float* pl   = pm + (size_t)2 * BHS_;

  float* xf = (float*)d_out;  // running x lives in d_out (fp32)

  const dim3 tb(32, 8);
  const size_t HH = (size_t)H_ * H_;
  transpose_cvt<<<dim3(H_/32, H_/32, L_), tb, 0, stream>>>(wq, WtQKV,        H_, H_, HH, 3*HH);
  transpose_cvt<<<dim3(H_/32, H_/32, L_), tb, 0, stream>>>(wk, WtQKV + HH,   H_, H_, HH, 3*HH);
  transpose_cvt<<<dim3(H_/32, H_/32, L_), tb, 0, stream>>>(wv, WtQKV + 2*HH, H_, H_, HH, 3*HH);
  transpose_cvt<<<dim3(H_/32, H_/32, L_), tb, 0, stream>>>(wo, WtO, H_, H_, HH, HH);
  transpose_cvt<<<dim3(F_/32, H_/32, L_), tb, 0, stream>>>(wi, WtI, H_, F_, (size_t)H_*F_, (size_t)H_*F_);
  transpose_cvt<<<dim3(H_/32, F_/32, L_), tb, 0, stream>>>(wf, WtF, F_, H_, (size_t)F_*H_, (size_t)F_*H_);
  mask_cvt<<<dim3((B_*S_*S_/4)/256), 256, 0, stream>>>((const float4*)mask, (bf16x4*)madd);
  init_x_kernel<<<dim3((M_ * H_ / 4) / 256), 256, 0, stream>>>(
      (const float4*)x, (float4*)xf, (bf16x4*)xb);

  for (int l = 0; l < L_; ++l) {
    // QKV fused (grid.z = 3), direct outputs
    gemm_qkv_kernel<<<dim3(H_/128, M_/128, 3), 256, 0, stream>>>(
        xb, WtQKV + (size_t)l * 3 * HH, WtQKV + (size_t)l * 3 * HH + HH,
        WtQKV + (size_t)l * 3 * HH + 2 * HH,
        bq + l * H_, bk + l * H_, bv + l * H_, qb, kbf, vt);
    // attention (kv-split=2, LDS-staged) + combine
    attn_kernel5<<<dim3(S_/64, NH_, B_*2), 256, 0, stream>>>(
        qb, kbf, vt, madd, pctx, pm, pl);
    attn_combine<<<dim3((BHS_ * 16) / 256), 256, 0, stream>>>(
        (const float4*)pctx, pm, pl, ctx);
    // O-proj: split-K=4, fp32 partials + residual reduce
    gemm128_kernel<3><<<dim3(H_/128, M_/128, 4), 256, 0, stream>>>(
        ctx, WtO + (size_t)l * HH, nullptr, nullptr, nullptr, nullptr,
        part, H_, H_, H_ / 4);
    reduce_residual<<<dim3((M_ * H_ / 4) / 256), 256, 0, stream>>>(
        (const float4*)part, bo + l * H_, aat + l, (float4*)xf, (bf16x4*)xb);
    // FFN1: direct gelu output
    gemm128_kernel<1><<<dim3(F_/128, M_/128), 256, 0, stream>>>(
        xb, WtI + (size_t)l * H_ * F_, bi + l * F_, itm, nullptr, nullptr,
        nullptr, F_, H_, H_);
    // FFN2: split-K=4, fp32 partials + residual reduce
    gemm128_kernel<3><<<dim3(H_/128, M_/128, 4), 256, 0, stream>>>(
        itm, WtF + (size_t)l * F_ * H_, nullptr, nullptr, nullptr, nullptr,
        part, H_, F_, F_ / 4);
    reduce_residual<<<dim3((M_ * H_ / 4) / 256), 256, 0, stream>>>(
        (const float4*)part, bf_ + l * H_, afn + l, (float4*)xf, (bf16x4*)xb);
  }
}

// Round 7
// 656.770 us; speedup vs baseline: 1.5424x; 1.0340x over previous
//
#include <hip/hip_runtime.h>
#include <cstdint>

#define B_  2
#define S_  1024
#define H_  1024
#define NH_ 16
#define DH_ 64
#define F_  4096
#define L_  4
#define M_  (B_*S_)        // 2048 rows in all GEMMs

typedef __bf16 bf16;
typedef __bf16 bf16x8 __attribute__((ext_vector_type(8)));
typedef __bf16 bf16x4 __attribute__((ext_vector_type(4)));
typedef __bf16 bf16x2 __attribute__((ext_vector_type(2)));
typedef float  f32x4  __attribute__((ext_vector_type(4)));

// ---------------- async global->LDS (16B per lane), CK-style addrspace cast ----
__device__ __forceinline__ void async_ld16(void* lds, const void* g) {
  auto* lp = reinterpret_cast<__attribute__((address_space(3))) unsigned int*>(
      reinterpret_cast<uintptr_t>(lds));
  const auto* gp = reinterpret_cast<const __attribute__((address_space(1))) unsigned int*>(
      reinterpret_cast<uintptr_t>(g));
  __builtin_amdgcn_global_load_lds(gp, lp, 16, 0, 0);
}

__device__ __forceinline__ float gelu_tanh(float x) {
  float u = 0.7978845608028654f * (x + 0.044715f * x * x * x);
  u = fminf(fmaxf(u, -15.f), 15.f);
  float e = __builtin_amdgcn_exp2f(u * 2.8853900817779268f); // exp(2u)
  return 0.5f * x * (1.f + (e - 1.f) / (e + 1.f));
}

// ---------------- weight transpose + fp32->bf16 convert:  W[K][N] -> Wt[N][K] --
__global__ __launch_bounds__(256) void transpose_cvt(
    const float* __restrict__ src, bf16* __restrict__ dst, int K, int N,
    size_t src_z, size_t dst_z) {
  __shared__ float t[32][33];
  const int n0 = blockIdx.x * 32, k0 = blockIdx.y * 32;
  const size_t so = (size_t)blockIdx.z * src_z;
  const size_t dz = (size_t)blockIdx.z * dst_z;
  const int x = threadIdx.x, y = threadIdx.y;
  #pragma unroll
  for (int i = 0; i < 32; i += 8)
    t[y + i][x] = src[so + (size_t)(k0 + y + i) * N + n0 + x];
  __syncthreads();
  #pragma unroll
  for (int i = 0; i < 32; i += 8)
    dst[dz + (size_t)(n0 + y + i) * K + k0 + x] = (bf16)t[x][y + i];
}

// ---------------- mask -> bf16 additive adder in log2 domain ------------------
__global__ __launch_bounds__(256) void mask_cvt(
    const float4* __restrict__ m, bf16x4* __restrict__ out) {
  const int i = blockIdx.x * 256 + (int)threadIdx.x;
  const float c2 = -10000.f * 1.44269504088896f;
  float4 v = m[i];
  bf16x4 o;
  o[0] = (bf16)((1.f - v.x) * c2);
  o[1] = (bf16)((1.f - v.y) * c2);
  o[2] = (bf16)((1.f - v.z) * c2);
  o[3] = (bf16)((1.f - v.w) * c2);
  out[i] = o;
}

// ---------------- x init: copy fp32 x -> xf (running x, = d_out) + bf16 mirror -
__global__ __launch_bounds__(256) void init_x_kernel(
    const float4* __restrict__ x, float4* __restrict__ xf, bf16x4* __restrict__ xb) {
  int i = blockIdx.x * 256 + threadIdx.x;
  float4 v = x[i];
  xf[i] = v;
  bf16x4 b;
  b[0] = (bf16)v.x; b[1] = (bf16)v.y; b[2] = (bf16)v.z; b[3] = (bf16)v.w;
  xb[i] = b;
}

// ---------------- double-buffered GEMM core: C[128x128] = A[.][ld] @ Bt[.][ld]^T
// T3-minimum schedule: STAGE(next) issued BEFORE compute(cur); the vmcnt(0)
// drain at the end-of-iter barrier lands AFTER the 16 MFMA.
__device__ __forceinline__ void gemm_core(
    const bf16* __restrict__ A, const bf16* __restrict__ Bt, int ld, int kLen,
    int m0, int n0, bf16* As, bf16* Bs, f32x4 (&acc)[4][4]) {
  const int tid = (int)threadIdx.x;
  const int w = tid >> 6, l = tid & 63;
  const int lr = l & 15, lg = l >> 4;
  const int wm = w >> 1, wn = w & 1;
  const int srow = l >> 2;            // 0..15 (staging row within 16-row chunk)
  const int scol = (l & 3) * 8;       // element offset (8 bf16 = 16B)

  const bf16* ag = A  + (size_t)(m0 + w * 32 + srow) * ld + scol;
  const bf16* bg = Bt + (size_t)(n0 + w * 32 + srow) * ld + scol;
  const int soff = (w * 32) * 32;

  auto stage = [&](int buf, int kk) {
    bf16* ad = As + buf * 4096 + soff;
    bf16* bd = Bs + buf * 4096 + soff;
    async_ld16(ad,           ag + kk);
    async_ld16(ad + 16 * 32, ag + kk + (size_t)16 * ld);
    async_ld16(bd,           bg + kk);
    async_ld16(bd + 16 * 32, bg + kk + (size_t)16 * ld);
  };

  stage(0, 0);
  __syncthreads();                    // vmcnt(0) drain: tile 0 ready
  int cur = 0;
  for (int k0 = 0; k0 < kLen; k0 += 32) {
    if (k0 + 32 < kLen) stage(cur ^ 1, k0 + 32);   // async prefetch next tile
    const bf16* Ab = As + cur * 4096;
    const bf16* Bb = Bs + cur * 4096;
    bf16x8 af[4], bv[4];
    #pragma unroll
    for (int i = 0; i < 4; ++i)
      af[i] = *(const bf16x8*)(Ab + (wm * 64 + i * 16 + lr) * 32 + lg * 8);
    #pragma unroll
    for (int i = 0; i < 4; ++i)
      bv[i] = *(const bf16x8*)(Bb + (wn * 64 + i * 16 + lr) * 32 + lg * 8);
    #pragma unroll
    for (int i = 0; i < 4; ++i)
      #pragma unroll
      for (int j = 0; j < 4; ++j)
        acc[i][j] = __builtin_amdgcn_mfma_f32_16x16x32_bf16(af[i], bv[j], acc[i][j], 0, 0, 0);
    __syncthreads();                  // drains prefetch (next tile ready), frees cur
    cur ^= 1;
  }
}

// MODE 1: out_bf16 = gelu(acc+bias) | MODE 3: fp32 partial -> part[z*M*N + idx]
template <int MODE>
__global__ __launch_bounds__(256) void gemm128_kernel(
    const bf16* __restrict__ A, const bf16* __restrict__ Bt,
    const float* __restrict__ bias, bf16* __restrict__ outb,
    float* __restrict__ part, int N, int K, int kSlice) {
  __shared__ __align__(16) bf16 As[2 * 128 * 32];
  __shared__ __align__(16) bf16 Bs[2 * 128 * 32];
  const int m0 = blockIdx.y * 128, n0 = blockIdx.x * 128;
  const int z = blockIdx.z;
  const f32x4 z4 = {0.f, 0.f, 0.f, 0.f};
  f32x4 acc[4][4];
  #pragma unroll
  for (int i = 0; i < 4; ++i)
    #pragma unroll
    for (int j = 0; j < 4; ++j) acc[i][j] = z4;

  gemm_core(A + (size_t)z * kSlice, Bt + (size_t)z * kSlice, K, kSlice,
            m0, n0, As, Bs, acc);

  const int tid = (int)threadIdx.x;
  const int w = tid >> 6, l = tid & 63;
  const int lr = l & 15, lg = l >> 4;
  const int wm = w >> 1, wn = w & 1;
  const size_t pbase = (MODE == 3) ? (size_t)z * M_ * (size_t)N : 0;
  #pragma unroll
  for (int i = 0; i < 4; ++i) {
    const int row0 = m0 + wm * 64 + i * 16 + lg * 4;
    #pragma unroll
    for (int j = 0; j < 4; ++j) {
      const int col = n0 + wn * 64 + j * 16 + lr;
      const float bvx = (MODE == 3) ? 0.f : bias[col];
      #pragma unroll
      for (int r = 0; r < 4; ++r) {
        const size_t idx = (size_t)(row0 + r) * N + col;
        float v = acc[i][j][r] + bvx;
        if (MODE == 3) {
          part[pbase + idx] = v;
        } else {
          outb[idx] = (bf16)gelu_tanh(v);
        }
      }
    }
  }
}

// ---------------- split-K reduce + bias + ReZero residual (fp32 partials, z=4) -
__global__ __launch_bounds__(256) void reduce_residual(
    const float4* __restrict__ part, const float* __restrict__ bias,
    const float* __restrict__ alphap, float4* __restrict__ xf,
    bf16x4* __restrict__ xb) {
  const int i = blockIdx.x * 256 + (int)threadIdx.x;   // over M_*H_/4
  const int nper = M_ * H_ / 4;
  float4 s = part[i];
  #pragma unroll
  for (int zz = 1; zz < 4; ++zz) {
    float4 p = part[i + (size_t)zz * nper];
    s.x += p.x; s.y += p.y; s.z += p.z; s.w += p.w;
  }
  const int col = (i * 4) & (H_ - 1);
  const float4 b4 = *(const float4*)(bias + col);
  const float a = *alphap;
  float4 xv = xf[i];
  xv.x += a * (s.x + b4.x);
  xv.y += a * (s.y + b4.y);
  xv.z += a * (s.z + b4.z);
  xv.w += a * (s.w + b4.w);
  xf[i] = xv;
  bf16x4 bb;
  bb[0] = (bf16)xv.x; bb[1] = (bf16)xv.y; bb[2] = (bf16)xv.z; bb[3] = (bf16)xv.w;
  xb[i] = bb;
}

// ---------------- QKV GEMM, BN=64 tile: grid (3072/64, M/128) = 768 blocks ----
// Wt = [3072][1024] (Q rows 0..1023, K 1024..2047, V 2048..3071). Each block's
// 64 output cols lie entirely in one of Q/K/V (and one head for V).
__global__ __launch_bounds__(256) void gemm_qkv64(
    const bf16* __restrict__ A, const bf16* __restrict__ Wt,
    const float* __restrict__ bq, const float* __restrict__ bk,
    const float* __restrict__ bvv,
    bf16* __restrict__ qo, bf16* __restrict__ ko, bf16* __restrict__ vt) {
  __shared__ __align__(16) bf16 As[2 * 128 * 32];   // 16KB
  __shared__ __align__(16) bf16 Bs[2 * 64 * 32];    //  8KB
  const int tid = (int)threadIdx.x;
  const int w = tid >> 6, l = tid & 63;
  const int lr = l & 15, lg = l >> 4;
  const int wm = w >> 1, wn = w & 1;
  const int srow = l >> 2, scol = (l & 3) * 8;
  const int m0 = blockIdx.y * 128, n0 = blockIdx.x * 64;

  const bf16* ag = A  + (size_t)(m0 + w * 32 + srow) * H_ + scol;
  const bf16* bg = Wt + (size_t)(n0 + w * 16 + srow) * H_ + scol;
  const int aoff = (w * 32) * 32;
  const int boff = (w * 16) * 32;

  auto stage = [&](int buf, int kk) {
    bf16* ad = As + buf * 4096 + aoff;
    bf16* bd = Bs + buf * 2048 + boff;
    async_ld16(ad,           ag + kk);
    async_ld16(ad + 16 * 32, ag + kk + (size_t)16 * H_);
    async_ld16(bd,           bg + kk);
  };

  const f32x4 z4 = {0.f, 0.f, 0.f, 0.f};
  f32x4 acc[4][2];
  #pragma unroll
  for (int i = 0; i < 4; ++i)
    #pragma unroll
    for (int j = 0; j < 2; ++j) acc[i][j] = z4;

  stage(0, 0);
  __syncthreads();
  int cur = 0;
  for (int k0 = 0; k0 < H_; k0 += 32) {
    if (k0 + 32 < H_) stage(cur ^ 1, k0 + 32);
    const bf16* Ab = As + cur * 4096;
    const bf16* Bb = Bs + cur * 2048;
    bf16x8 af[4], bv[2];
    #pragma unroll
    for (int i = 0; i < 4; ++i)
      af[i] = *(const bf16x8*)(Ab + (wm * 64 + i * 16 + lr) * 32 + lg * 8);
    #pragma unroll
    for (int j = 0; j < 2; ++j)
      bv[j] = *(const bf16x8*)(Bb + (wn * 32 + j * 16 + lr) * 32 + lg * 8);
    #pragma unroll
    for (int i = 0; i < 4; ++i)
      #pragma unroll
      for (int j = 0; j < 2; ++j)
        acc[i][j] = __builtin_amdgcn_mfma_f32_16x16x32_bf16(af[i], bv[j], acc[i][j], 0, 0, 0);
    __syncthreads();
    cur ^= 1;
  }

  if (n0 < 2048) {  // Q or K: direct [B,S,H] store
    bf16* out = (n0 < 1024) ? qo : ko;
    const float* bias = (n0 < 1024) ? bq : bk;
    const int nl = n0 & 1023;
    #pragma unroll
    for (int i = 0; i < 4; ++i) {
      const int row0 = m0 + wm * 64 + i * 16 + lg * 4;
      #pragma unroll
      for (int j = 0; j < 2; ++j) {
        const int col = nl + wn * 32 + j * 16 + lr;
        const float bvx = bias[col];
        #pragma unroll
        for (int r = 0; r < 4; ++r)
          out[(size_t)(row0 + r) * H_ + col] = (bf16)(acc[i][j][r] + bvx);
      }
    }
  } else {          // V: transposed store Vt[((b*NH+h)*DH+d)*S + s]
    const int hh = (n0 >> 6) - 32;
    #pragma unroll
    for (int i = 0; i < 4; ++i) {
      const int row0 = m0 + wm * 64 + i * 16 + lg * 4;
      const int bb = row0 >> 10, ss = row0 & (S_ - 1);
      #pragma unroll
      for (int j = 0; j < 2; ++j) {
        const int dd = wn * 32 + j * 16 + lr;
        const float bvx = bvv[hh * 64 + dd];
        bf16x4 pk;
        #pragma unroll
        for (int r = 0; r < 4; ++r) pk[r] = (bf16)(acc[i][j][r] + bvx);
        *(bf16x4*)(vt + (((size_t)(bb * NH_ + hh) * DH_ + dd) << 10) + ss) = pk;
      }
    }
  }
}

// ---------------- flash attention v6: LDS-staged K/V, no kv-split -------------
// grid (S/64, NH, B), 256 thr = 4 waves. Swapped QK^T (lane-local softmax);
// in-kernel normalization, direct bf16 ctx write.
__global__ __launch_bounds__(256) void attn_kernel6(
    const bf16* __restrict__ Q, const bf16* __restrict__ Kb,
    const bf16* __restrict__ Vt, const bf16* __restrict__ madd,
    bf16* __restrict__ Ctx) {
  const int tid = (int)threadIdx.x;
  const int w = tid >> 6, l = tid & 63;
  const int lr = l & 15, lg = l >> 4;
  const int r7 = lr & 7;
  const int h = blockIdx.y, b = blockIdx.z;
  const int q0 = blockIdx.x * 64 + w * 16;

  __shared__ __align__(16) bf16 Kt[2][64 * 64];  // [buf][kv][d] swizzled
  __shared__ __align__(16) bf16 Vs[2][64 * 64];  // [buf][d][kv] swizzled
  __shared__ unsigned int Pu[4][16][36];         // per-wave P, u32-packed bf16

  const bf16* qp = Q + ((size_t)(b * S_ + q0 + lr)) * H_ + h * DH_;
  const bf16x8 qa0 = *(const bf16x8*)(qp + lg * 8);
  const bf16x8 qa1 = *(const bf16x8*)(qp + 32 + lg * 8);

  const f32x4 z4 = {0.f, 0.f, 0.f, 0.f};
  f32x4 acc[4];
  #pragma unroll
  for (int dt = 0; dt < 4; ++dt) acc[dt] = z4;
  float mrow = -1e30f, ssum = 0.f;

  const bf16* Kbase = Kb + ((size_t)b * S_) * H_ + h * DH_;
  const bf16* Vbase = Vt + ((size_t)(b * NH_ + h)) * DH_ * S_;
  const bf16* Mb = madd + ((size_t)(b * S_ + q0 + lr)) * S_;

  const float c1 = 0.125f * 1.44269504088896f;   // scale * log2(e)
  const float THR = 10.f;                        // defer-max headroom (base-2)

  const int sub = l >> 3;
  const int cs  = ((l & 7) ^ sub) * 8;
  auto stage = [&](int buf, int kv) {
    #pragma unroll
    for (int j = 0; j < 2; ++j) {
      const int rbase = w * 16 + j * 8;
      async_ld16(&Kt[buf][rbase * 64],
                 Kbase + (size_t)(kv + rbase + sub) * H_ + cs);
      async_ld16(&Vs[buf][rbase * 64],
                 Vbase + (size_t)(rbase + sub) * S_ + kv + cs);
    }
  };

  stage(0, 0);
  __syncthreads();                    // vmcnt(0) drain: tile 0 ready
  int cur = 0;
  #pragma unroll 1
  for (int it = 0; it < 16; ++it) {
    const int kv0 = it * 64;
    if (it < 15) stage(cur ^ 1, kv0 + 64);   // async prefetch next tile
    const bf16* Kc = &Kt[cur][0];
    const bf16* Vc = &Vs[cur][0];
    bf16x8 kf0[4], kf1[4];
    bf16x4 mk[4];
    #pragma unroll
    for (int t = 0; t < 4; ++t) {
      kf0[t] = *(const bf16x8*)(Kc + (t * 16 + lr) * 64 + ((lg ^ r7) * 8));
      kf1[t] = *(const bf16x8*)(Kc + (t * 16 + lr) * 64 + (((4 + lg) ^ r7) * 8));
      mk[t] = *(const bf16x4*)(Mb + kv0 + t * 16 + lg * 4);
    }
    f32x4 st[4];
    __builtin_amdgcn_s_setprio(1);
    #pragma unroll
    for (int t = 0; t < 4; ++t) {
      f32x4 s = __builtin_amdgcn_mfma_f32_16x16x32_bf16(kf0[t], qa0, z4, 0, 0, 0);
      st[t] = __builtin_amdgcn_mfma_f32_16x16x32_bf16(kf1[t], qa1, s, 0, 0, 0);
    }
    __builtin_amdgcn_s_setprio(0);
    float sv[4][4];
    #pragma unroll
    for (int t = 0; t < 4; ++t)
      #pragma unroll
      for (int r = 0; r < 4; ++r)
        sv[t][r] = st[t][r] * c1 + (float)mk[t][r];
    float nm = sv[0][0];
    #pragma unroll
    for (int t = 0; t < 4; ++t)
      #pragma unroll
      for (int r = 0; r < 4; ++r) nm = fmaxf(nm, sv[t][r]);
    nm = fmaxf(nm, __shfl_xor(nm, 16));
    nm = fmaxf(nm, __shfl_xor(nm, 32));
    if (__any(nm > mrow + THR)) {
      float newm = fmaxf(mrow, nm);
      float f = __builtin_amdgcn_exp2f(mrow - newm);
      mrow = newm;
      ssum *= f;
      #pragma unroll
      for (int dt = 0; dt < 4; ++dt)
        #pragma unroll
        for (int r = 0; r < 4; ++r) acc[dt][r] *= f;
    }
    float p[4][4];
    float ps = 0.f;
    #pragma unroll
    for (int t = 0; t < 4; ++t)
      #pragma unroll
      for (int r = 0; r < 4; ++r) {
        p[t][r] = __builtin_amdgcn_exp2f(sv[t][r] - mrow);
        ps += p[t][r];
      }
    ps += __shfl_xor(ps, 16);
    ps += __shfl_xor(ps, 32);
    ssum += ps;
    #pragma unroll
    for (int t = 0; t < 4; ++t)
      #pragma unroll
      for (int hh = 0; hh < 2; ++hh) {
        union { bf16x2 v; unsigned int u; } pk;
        pk.v[0] = (bf16)p[t][2 * hh];
        pk.v[1] = (bf16)p[t][2 * hh + 1];
        Pu[w][lr][8 * t + 2 * lg + hh] = pk.u;
      }
    const bf16x8 pf0 = *(const bf16x8*)&Pu[w][lr][4 * lg];
    const bf16x8 pf1 = *(const bf16x8*)&Pu[w][lr][16 + 4 * lg];
    __builtin_amdgcn_s_setprio(1);
    #pragma unroll
    for (int dt = 0; dt < 4; ++dt) {
      bf16x8 vb0 = *(const bf16x8*)(Vc + (dt * 16 + lr) * 64 + ((lg ^ r7) * 8));
      acc[dt] = __builtin_amdgcn_mfma_f32_16x16x32_bf16(vb0, pf0, acc[dt], 0, 0, 0);
    }
    #pragma unroll
    for (int dt = 0; dt < 4; ++dt) {
      bf16x8 vb1 = *(const bf16x8*)(Vc + (dt * 16 + lr) * 64 + (((4 + lg) ^ r7) * 8));
      acc[dt] = __builtin_amdgcn_mfma_f32_16x16x32_bf16(vb1, pf1, acc[dt], 0, 0, 0);
    }
    __builtin_amdgcn_s_setprio(0);
    __syncthreads();                  // drains prefetch (next tile ready), frees cur
    cur ^= 1;
  }
  // --- normalize + direct bf16 ctx write (lane owns q-row = lr) -------------
  const float inv = 1.f / ssum;
  bf16* cp = Ctx + ((size_t)(b * S_ + q0 + lr)) * H_ + h * DH_;
  #pragma unroll
  for (int dt = 0; dt < 4; ++dt) {
    bf16x4 o;
    #pragma unroll
    for (int r = 0; r < 4; ++r) o[r] = (bf16)(acc[dt][r] * inv);
    *(bf16x4*)(cp + dt * 16 + lg * 4) = o;
  }
}

// ---------------- launcher ----------------------------------------------------
extern "C" void kernel_launch(void* const* d_in, const int* in_sizes, int n_in,
                              void* d_out, int out_size, void* d_ws, size_t ws_size,
                              hipStream_t stream) {
  (void)in_sizes; (void)n_in; (void)out_size; (void)ws_size;
  const float* x    = (const float*)d_in[0];
  const float* mask = (const float*)d_in[1];
  const float* wq   = (const float*)d_in[2];
  const float* bq   = (const float*)d_in[3];
  const float* wk   = (const float*)d_in[4];
  const float* bk   = (const float*)d_in[5];
  const float* wv   = (const float*)d_in[6];
  const float* bv   = (const float*)d_in[7];
  const float* wo   = (const float*)d_in[8];
  const float* bo   = (const float*)d_in[9];
  const float* aat  = (const float*)d_in[10];
  const float* wi   = (const float*)d_in[11];
  const float* bi   = (const float*)d_in[12];
  const float* wf   = (const float*)d_in[13];
  const float* bf_  = (const float*)d_in[14];
  const float* afn  = (const float*)d_in[15];

  char* ws = (char*)d_ws;
  size_t o = 0;
  bf16* WtQKV = (bf16*)(ws + o); o += (size_t)L_ * 3 * H_ * H_ * 2; // 24MB [L][3072][1024]
  bf16* WtO = (bf16*)(ws + o); o += (size_t)L_ * H_ * H_ * 2;       //  8MB
  bf16* WtI = (bf16*)(ws + o); o += (size_t)L_ * H_ * F_ * 2;       // 32MB
  bf16* WtF = (bf16*)(ws + o); o += (size_t)L_ * F_ * H_ * 2;       // 32MB
  bf16* madd = (bf16*)(ws + o); o += (size_t)B_ * S_ * S_ * 2;      //  4MB
  bf16* xb  = (bf16*)(ws + o); o += (size_t)M_ * H_ * 2;            //  4MB
  bf16* qb  = (bf16*)(ws + o); o += (size_t)M_ * H_ * 2;
  bf16* kbf = (bf16*)(ws + o); o += (size_t)M_ * H_ * 2;
  bf16* vt  = (bf16*)(ws + o); o += (size_t)M_ * H_ * 2;
  bf16* ctx = (bf16*)(ws + o); o += (size_t)M_ * H_ * 2;
  bf16* itm = (bf16*)(ws + o); o += (size_t)M_ * F_ * 2;            // 16MB
  float* part = (float*)(ws + o); o += (size_t)4 * M_ * H_ * 4;     // 32MB (168MB total)

  float* xf = (float*)d_out;  // running x lives in d_out (fp32)

  const dim3 tb(32, 8);
  const size_t HH = (size_t)H_ * H_;
  transpose_cvt<<<dim3(H_/32, H_/32, L_), tb, 0, stream>>>(wq, WtQKV,        H_, H_, HH, 3*HH);
  transpose_cvt<<<dim3(H_/32, H_/32, L_), tb, 0, stream>>>(wk, WtQKV + HH,   H_, H_, HH, 3*HH);
  transpose_cvt<<<dim3(H_/32, H_/32, L_), tb, 0, stream>>>(wv, WtQKV + 2*HH, H_, H_, HH, 3*HH);
  transpose_cvt<<<dim3(H_/32, H_/32, L_), tb, 0, stream>>>(wo, WtO, H_, H_, HH, HH);
  transpose_cvt<<<dim3(F_/32, H_/32, L_), tb, 0, stream>>>(wi, WtI, H_, F_, (size_t)H_*F_, (size_t)H_*F_);
  transpose_cvt<<<dim3(H_/32, F_/32, L_), tb, 0, stream>>>(wf, WtF, F_, H_, (size_t)F_*H_, (size_t)F_*H_);
  mask_cvt<<<dim3((B_*S_*S_/4)/256), 256, 0, stream>>>((const float4*)mask, (bf16x4*)madd);
  init_x_kernel<<<dim3((M_ * H_ / 4) / 256), 256, 0, stream>>>(
      (const float4*)x, (float4*)xf, (bf16x4*)xb);

  for (int l = 0; l < L_; ++l) {
    // QKV: BN=64 tiles, 768 blocks = 3/CU exact fill
    gemm_qkv64<<<dim3(48, M_/128), 256, 0, stream>>>(
        xb, WtQKV + (size_t)l * 3 * HH,
        bq + l * H_, bk + l * H_, bv + l * H_, qb, kbf, vt);
    // attention: no kv-split, direct normalized ctx write
    attn_kernel6<<<dim3(S_/64, NH_, B_), 256, 0, stream>>>(
        qb, kbf, vt, madd, ctx);
    // O-proj: split-K=4, fp32 partials + residual reduce
    gemm128_kernel<3><<<dim3(H_/128, M_/128, 4), 256, 0, stream>>>(
        ctx, WtO + (size_t)l * HH, nullptr, nullptr, part, H_, H_, H_ / 4);
    reduce_residual<<<dim3((M_ * H_ / 4) / 256), 256, 0, stream>>>(
        (const float4*)part, bo + l * H_, aat + l, (float4*)xf, (bf16x4*)xb);
    // FFN1: direct gelu output
    gemm128_kernel<1><<<dim3(F_/128, M_/128), 256, 0, stream>>>(
        xb, WtI + (size_t)l * H_ * F_, bi + l * F_, itm, nullptr, F_, H_, H_);
    // FFN2: split-K=4, fp32 partials + residual reduce
    gemm128_kernel<3><<<dim3(H_/128, M_/128, 4), 256, 0, stream>>>(
        itm, WtF + (size_t)l * F_ * H_, nullptr, nullptr, part, H_, F_, F_ / 4);
    reduce_residual<<<dim3((M_ * H_ / 4) / 256), 256, 0, stream>>>(
        (const float4*)part, bf_ + l * H_, afn + l, (float4*)xf, (bf16x4*)xb);
  }
}

// Round 8
// 631.685 us; speedup vs baseline: 1.6036x; 1.0397x over previous
//
#include <hip/hip_runtime.h>
#include <cstdint>

#define B_  2
#define S_  1024
#define H_  1024
#define NH_ 16
#define DH_ 64
#define F_  4096
#define L_  4
#define M_  (B_*S_)        // 2048 rows in all GEMMs

typedef __bf16 bf16;
typedef __bf16 bf16x8 __attribute__((ext_vector_type(8)));
typedef __bf16 bf16x4 __attribute__((ext_vector_type(4)));
typedef __bf16 bf16x2 __attribute__((ext_vector_type(2)));
typedef float  f32x4  __attribute__((ext_vector_type(4)));

// ---------------- async global->LDS (16B per lane), CK-style addrspace cast ----
__device__ __forceinline__ void async_ld16(void* lds, const void* g) {
  auto* lp = reinterpret_cast<__attribute__((address_space(3))) unsigned int*>(
      reinterpret_cast<uintptr_t>(lds));
  const auto* gp = reinterpret_cast<const __attribute__((address_space(1))) unsigned int*>(
      reinterpret_cast<uintptr_t>(g));
  __builtin_amdgcn_global_load_lds(gp, lp, 16, 0, 0);
}

__device__ __forceinline__ float gelu_tanh(float x) {
  float u = 0.7978845608028654f * (x + 0.044715f * x * x * x);
  u = fminf(fmaxf(u, -15.f), 15.f);
  float e = __builtin_amdgcn_exp2f(u * 2.8853900817779268f); // exp(2u)
  return 0.5f * x * (1.f + (e - 1.f) / (e + 1.f));
}

// ---------------- fused weight transpose+cvt: all 6 weights, one launch -------
// Segments (blockIdx.x): [0,16384) wq/wk/wv/wo (1024 tiles/l each);
// [16384,32768) wi (4096 tiles/l); [32768,49152) wf (4096 tiles/l).
__global__ __launch_bounds__(256) void transpose_all(
    const float* __restrict__ wq, const float* __restrict__ wk,
    const float* __restrict__ wv, const float* __restrict__ wo,
    const float* __restrict__ wi, const float* __restrict__ wf,
    bf16* __restrict__ WtQKV, bf16* __restrict__ WtO,
    bf16* __restrict__ WtI, bf16* __restrict__ WtF) {
  const size_t HH = (size_t)H_ * H_;
  const size_t HF = (size_t)H_ * F_;
  int idx = blockIdx.x;
  const float* src;
  bf16* dst;
  int N, k0, n0;
  if (idx < 16384) {
    const int s = idx >> 12; idx &= 4095;          // which of wq/wk/wv/wo
    const int l = idx >> 10; idx &= 1023;
    n0 = (idx & 31) * 32; k0 = (idx >> 5) * 32;
    N = H_;
    src = (s == 0 ? wq : s == 1 ? wk : s == 2 ? wv : wo) + (size_t)l * HH;
    dst = (s < 3) ? (WtQKV + (size_t)l * 3 * HH + (size_t)s * HH)
                  : (WtO + (size_t)l * HH);
  } else if (idx < 32768) {
    idx -= 16384;
    const int l = idx >> 12; idx &= 4095;          // wi [1024][4096]
    n0 = (idx & 127) * 32; k0 = (idx >> 7) * 32;
    N = F_;
    src = wi + (size_t)l * HF;
    dst = WtI + (size_t)l * HF;
  } else {
    idx -= 32768;
    const int l = idx >> 12; idx &= 4095;          // wf [4096][1024]
    n0 = (idx & 31) * 32; k0 = (idx >> 5) * 32;
    N = H_;
    src = wf + (size_t)l * HF;
    dst = WtF + (size_t)l * HF;
  }
  const int K = (N == H_ && src >= wf && src < wf + (size_t)L_ * HF) ? F_ : H_;
  __shared__ float t[32][33];
  const int x = threadIdx.x, y = threadIdx.y;
  #pragma unroll
  for (int i = 0; i < 32; i += 8)
    t[y + i][x] = src[(size_t)(k0 + y + i) * N + n0 + x];
  __syncthreads();
  #pragma unroll
  for (int i = 0; i < 32; i += 8)
    dst[(size_t)(n0 + y + i) * K + k0 + x] = (bf16)t[x][y + i];
}

// ---------------- fused prep: mask->bf16 log2 adder + x init ------------------
// blocks [0,2048): madd; [2048,4096): xf/xb init. Both 524288 float4 items.
__global__ __launch_bounds__(256) void prep_kernel(
    const float4* __restrict__ mask, bf16x4* __restrict__ madd,
    const float4* __restrict__ x, float4* __restrict__ xf,
    bf16x4* __restrict__ xb) {
  const int blk = blockIdx.x;
  if (blk < 2048) {
    const int i = blk * 256 + (int)threadIdx.x;
    const float c2 = -10000.f * 1.44269504088896f;
    float4 v = mask[i];
    bf16x4 o;
    o[0] = (bf16)((1.f - v.x) * c2);
    o[1] = (bf16)((1.f - v.y) * c2);
    o[2] = (bf16)((1.f - v.z) * c2);
    o[3] = (bf16)((1.f - v.w) * c2);
    madd[i] = o;
  } else {
    const int i = (blk - 2048) * 256 + (int)threadIdx.x;
    float4 v = x[i];
    xf[i] = v;
    bf16x4 b;
    b[0] = (bf16)v.x; b[1] = (bf16)v.y; b[2] = (bf16)v.z; b[3] = (bf16)v.w;
    xb[i] = b;
  }
}

// ---------------- double-buffered GEMM core: C[128x128] = A[.][ld] @ Bt[.][ld]^T
__device__ __forceinline__ void gemm_core(
    const bf16* __restrict__ A, const bf16* __restrict__ Bt, int ld, int kLen,
    int m0, int n0, bf16* As, bf16* Bs, f32x4 (&acc)[4][4]) {
  const int tid = (int)threadIdx.x;
  const int w = tid >> 6, l = tid & 63;
  const int lr = l & 15, lg = l >> 4;
  const int wm = w >> 1, wn = w & 1;
  const int srow = l >> 2;
  const int scol = (l & 3) * 8;

  const bf16* ag = A  + (size_t)(m0 + w * 32 + srow) * ld + scol;
  const bf16* bg = Bt + (size_t)(n0 + w * 32 + srow) * ld + scol;
  const int soff = (w * 32) * 32;

  auto stage = [&](int buf, int kk) {
    bf16* ad = As + buf * 4096 + soff;
    bf16* bd = Bs + buf * 4096 + soff;
    async_ld16(ad,           ag + kk);
    async_ld16(ad + 16 * 32, ag + kk + (size_t)16 * ld);
    async_ld16(bd,           bg + kk);
    async_ld16(bd + 16 * 32, bg + kk + (size_t)16 * ld);
  };

  stage(0, 0);
  __syncthreads();
  int cur = 0;
  for (int k0 = 0; k0 < kLen; k0 += 32) {
    if (k0 + 32 < kLen) stage(cur ^ 1, k0 + 32);
    const bf16* Ab = As + cur * 4096;
    const bf16* Bb = Bs + cur * 4096;
    bf16x8 af[4], bv[4];
    #pragma unroll
    for (int i = 0; i < 4; ++i)
      af[i] = *(const bf16x8*)(Ab + (wm * 64 + i * 16 + lr) * 32 + lg * 8);
    #pragma unroll
    for (int i = 0; i < 4; ++i)
      bv[i] = *(const bf16x8*)(Bb + (wn * 64 + i * 16 + lr) * 32 + lg * 8);
    #pragma unroll
    for (int i = 0; i < 4; ++i)
      #pragma unroll
      for (int j = 0; j < 4; ++j)
        acc[i][j] = __builtin_amdgcn_mfma_f32_16x16x32_bf16(af[i], bv[j], acc[i][j], 0, 0, 0);
    __syncthreads();
    cur ^= 1;
  }
}

// MODE 1: out_bf16 = gelu(acc+bias) | MODE 3: fp32 partial -> part[z*M*N + idx]
template <int MODE>
__global__ __launch_bounds__(256) void gemm128_kernel(
    const bf16* __restrict__ A, const bf16* __restrict__ Bt,
    const float* __restrict__ bias, bf16* __restrict__ outb,
    float* __restrict__ part, int N, int K, int kSlice) {
  __shared__ __align__(16) bf16 As[2 * 128 * 32];
  __shared__ __align__(16) bf16 Bs[2 * 128 * 32];
  const int m0 = blockIdx.y * 128, n0 = blockIdx.x * 128;
  const int z = blockIdx.z;
  const f32x4 z4 = {0.f, 0.f, 0.f, 0.f};
  f32x4 acc[4][4];
  #pragma unroll
  for (int i = 0; i < 4; ++i)
    #pragma unroll
    for (int j = 0; j < 4; ++j) acc[i][j] = z4;

  gemm_core(A + (size_t)z * kSlice, Bt + (size_t)z * kSlice, K, kSlice,
            m0, n0, As, Bs, acc);

  const int tid = (int)threadIdx.x;
  const int w = tid >> 6, l = tid & 63;
  const int lr = l & 15, lg = l >> 4;
  const int wm = w >> 1, wn = w & 1;
  const size_t pbase = (MODE == 3) ? (size_t)z * M_ * (size_t)N : 0;
  #pragma unroll
  for (int i = 0; i < 4; ++i) {
    const int row0 = m0 + wm * 64 + i * 16 + lg * 4;
    #pragma unroll
    for (int j = 0; j < 4; ++j) {
      const int col = n0 + wn * 64 + j * 16 + lr;
      const float bvx = (MODE == 3) ? 0.f : bias[col];
      #pragma unroll
      for (int r = 0; r < 4; ++r) {
        const size_t idx = (size_t)(row0 + r) * N + col;
        float v = acc[i][j][r] + bvx;
        if (MODE == 3) {
          part[pbase + idx] = v;
        } else {
          outb[idx] = (bf16)gelu_tanh(v);
        }
      }
    }
  }
}

// ---------------- split-K reduce + bias + ReZero residual (fp32 partials, z=4) -
__global__ __launch_bounds__(256) void reduce_residual(
    const float4* __restrict__ part, const float* __restrict__ bias,
    const float* __restrict__ alphap, float4* __restrict__ xf,
    bf16x4* __restrict__ xb) {
  const int i = blockIdx.x * 256 + (int)threadIdx.x;   // over M_*H_/4
  const int nper = M_ * H_ / 4;
  float4 s = part[i];
  #pragma unroll
  for (int zz = 1; zz < 4; ++zz) {
    float4 p = part[i + (size_t)zz * nper];
    s.x += p.x; s.y += p.y; s.z += p.z; s.w += p.w;
  }
  const int col = (i * 4) & (H_ - 1);
  const float4 b4 = *(const float4*)(bias + col);
  const float a = *alphap;
  float4 xv = xf[i];
  xv.x += a * (s.x + b4.x);
  xv.y += a * (s.y + b4.y);
  xv.z += a * (s.z + b4.z);
  xv.w += a * (s.w + b4.w);
  xf[i] = xv;
  bf16x4 bb;
  bb[0] = (bf16)xv.x; bb[1] = (bf16)xv.y; bb[2] = (bf16)xv.z; bb[3] = (bf16)xv.w;
  xb[i] = bb;
}

// ---------------- QKV GEMM, BN=64 tile: grid (48, 16) = 768 blocks ------------
__global__ __launch_bounds__(256) void gemm_qkv64(
    const bf16* __restrict__ A, const bf16* __restrict__ Wt,
    const float* __restrict__ bq, const float* __restrict__ bk,
    const float* __restrict__ bvv,
    bf16* __restrict__ qo, bf16* __restrict__ ko, bf16* __restrict__ vt) {
  __shared__ __align__(16) bf16 As[2 * 128 * 32];
  __shared__ __align__(16) bf16 Bs[2 * 64 * 32];
  const int tid = (int)threadIdx.x;
  const int w = tid >> 6, l = tid & 63;
  const int lr = l & 15, lg = l >> 4;
  const int wm = w >> 1, wn = w & 1;
  const int srow = l >> 2, scol = (l & 3) * 8;
  const int m0 = blockIdx.y * 128, n0 = blockIdx.x * 64;

  const bf16* ag = A  + (size_t)(m0 + w * 32 + srow) * H_ + scol;
  const bf16* bg = Wt + (size_t)(n0 + w * 16 + srow) * H_ + scol;
  const int aoff = (w * 32) * 32;
  const int boff = (w * 16) * 32;

  auto stage = [&](int buf, int kk) {
    bf16* ad = As + buf * 4096 + aoff;
    bf16* bd = Bs + buf * 2048 + boff;
    async_ld16(ad,           ag + kk);
    async_ld16(ad + 16 * 32, ag + kk + (size_t)16 * H_);
    async_ld16(bd,           bg + kk);
  };

  const f32x4 z4 = {0.f, 0.f, 0.f, 0.f};
  f32x4 acc[4][2];
  #pragma unroll
  for (int i = 0; i < 4; ++i)
    #pragma unroll
    for (int j = 0; j < 2; ++j) acc[i][j] = z4;

  stage(0, 0);
  __syncthreads();
  int cur = 0;
  for (int k0 = 0; k0 < H_; k0 += 32) {
    if (k0 + 32 < H_) stage(cur ^ 1, k0 + 32);
    const bf16* Ab = As + cur * 4096;
    const bf16* Bb = Bs + cur * 2048;
    bf16x8 af[4], bv[2];
    #pragma unroll
    for (int i = 0; i < 4; ++i)
      af[i] = *(const bf16x8*)(Ab + (wm * 64 + i * 16 + lr) * 32 + lg * 8);
    #pragma unroll
    for (int j = 0; j < 2; ++j)
      bv[j] = *(const bf16x8*)(Bb + (wn * 32 + j * 16 + lr) * 32 + lg * 8);
    #pragma unroll
    for (int i = 0; i < 4; ++i)
      #pragma unroll
      for (int j = 0; j < 2; ++j)
        acc[i][j] = __builtin_amdgcn_mfma_f32_16x16x32_bf16(af[i], bv[j], acc[i][j], 0, 0, 0);
    __syncthreads();
    cur ^= 1;
  }

  if (n0 < 2048) {  // Q or K: direct [B,S,H] store
    bf16* out = (n0 < 1024) ? qo : ko;
    const float* bias = (n0 < 1024) ? bq : bk;
    const int nl = n0 & 1023;
    #pragma unroll
    for (int i = 0; i < 4; ++i) {
      const int row0 = m0 + wm * 64 + i * 16 + lg * 4;
      #pragma unroll
      for (int j = 0; j < 2; ++j) {
        const int col = nl + wn * 32 + j * 16 + lr;
        const float bvx = bias[col];
        #pragma unroll
        for (int r = 0; r < 4; ++r)
          out[(size_t)(row0 + r) * H_ + col] = (bf16)(acc[i][j][r] + bvx);
      }
    }
  } else {          // V: transposed store Vt[((b*NH+h)*DH+d)*S + s]
    const int hh = (n0 >> 6) - 32;
    #pragma unroll
    for (int i = 0; i < 4; ++i) {
      const int row0 = m0 + wm * 64 + i * 16 + lg * 4;
      const int bb = row0 >> 10, ss = row0 & (S_ - 1);
      #pragma unroll
      for (int j = 0; j < 2; ++j) {
        const int dd = wn * 32 + j * 16 + lr;
        const float bvx = bvv[hh * 64 + dd];
        bf16x4 pk;
        #pragma unroll
        for (int r = 0; r < 4; ++r) pk[r] = (bf16)(acc[i][j][r] + bvx);
        *(bf16x4*)(vt + (((size_t)(bb * NH_ + hh) * DH_ + dd) << 10) + ss) = pk;
      }
    }
  }
}

// ---------------- flash attention v7: LDS-staged K/V + mask reg-pipeline ------
__global__ __launch_bounds__(256) void attn_kernel7(
    const bf16* __restrict__ Q, const bf16* __restrict__ Kb,
    const bf16* __restrict__ Vt, const bf16* __restrict__ madd,
    bf16* __restrict__ Ctx) {
  const int tid = (int)threadIdx.x;
  const int w = tid >> 6, l = tid & 63;
  const int lr = l & 15, lg = l >> 4;
  const int r7 = lr & 7;
  const int h = blockIdx.y, b = blockIdx.z;
  const int q0 = blockIdx.x * 64 + w * 16;

  __shared__ __align__(16) bf16 Kt[2][64 * 64];  // [buf][kv][d] swizzled
  __shared__ __align__(16) bf16 Vs[2][64 * 64];  // [buf][d][kv] swizzled
  __shared__ unsigned int Pu[4][16][36];         // per-wave P, u32-packed bf16

  const bf16* qp = Q + ((size_t)(b * S_ + q0 + lr)) * H_ + h * DH_;
  const bf16x8 qa0 = *(const bf16x8*)(qp + lg * 8);
  const bf16x8 qa1 = *(const bf16x8*)(qp + 32 + lg * 8);

  const f32x4 z4 = {0.f, 0.f, 0.f, 0.f};
  f32x4 acc[4];
  #pragma unroll
  for (int dt = 0; dt < 4; ++dt) acc[dt] = z4;
  float mrow = -1e30f, ssum = 0.f;

  const bf16* Kbase = Kb + ((size_t)b * S_) * H_ + h * DH_;
  const bf16* Vbase = Vt + ((size_t)(b * NH_ + h)) * DH_ * S_;
  const bf16* Mb = madd + ((size_t)(b * S_ + q0 + lr)) * S_;

  const float c1 = 0.125f * 1.44269504088896f;   // scale * log2(e)
  const float THR = 10.f;                        // defer-max headroom (base-2)

  const int sub = l >> 3;
  const int cs  = ((l & 7) ^ sub) * 8;
  auto stage = [&](int buf, int kv) {
    #pragma unroll
    for (int j = 0; j < 2; ++j) {
      const int rbase = w * 16 + j * 8;
      async_ld16(&Kt[buf][rbase * 64],
                 Kbase + (size_t)(kv + rbase + sub) * H_ + cs);
      async_ld16(&Vs[buf][rbase * 64],
                 Vbase + (size_t)(rbase + sub) * S_ + kv + cs);
    }
  };

  stage(0, 0);
  // mask for tile 0 (register-pipelined one tile ahead thereafter)
  bf16x4 mk[4];
  #pragma unroll
  for (int t = 0; t < 4; ++t) mk[t] = *(const bf16x4*)(Mb + t * 16 + lg * 4);
  __syncthreads();                    // vmcnt(0) drain: tile 0 ready
  int cur = 0;
  #pragma unroll 1
  for (int it = 0; it < 16; ++it) {
    const int kv0 = it * 64;
    if (it < 15) stage(cur ^ 1, kv0 + 64);   // async prefetch next K/V tile
    // prefetch next mask tile into registers (independent of this iter's math)
    bf16x4 mkn[4];
    if (it < 15) {
      #pragma unroll
      for (int t = 0; t < 4; ++t)
        mkn[t] = *(const bf16x4*)(Mb + kv0 + 64 + t * 16 + lg * 4);
    }
    const bf16* Kc = &Kt[cur][0];
    const bf16* Vc = &Vs[cur][0];
    bf16x8 kf0[4], kf1[4];
    #pragma unroll
    for (int t = 0; t < 4; ++t) {
      kf0[t] = *(const bf16x8*)(Kc + (t * 16 + lr) * 64 + ((lg ^ r7) * 8));
      kf1[t] = *(const bf16x8*)(Kc + (t * 16 + lr) * 64 + (((4 + lg) ^ r7) * 8));
    }
    f32x4 st[4];
    __builtin_amdgcn_s_setprio(1);
    #pragma unroll
    for (int t = 0; t < 4; ++t) {
      f32x4 s = __builtin_amdgcn_mfma_f32_16x16x32_bf16(kf0[t], qa0, z4, 0, 0, 0);
      st[t] = __builtin_amdgcn_mfma_f32_16x16x32_bf16(kf1[t], qa1, s, 0, 0, 0);
    }
    __builtin_amdgcn_s_setprio(0);
    float sv[4][4];
    #pragma unroll
    for (int t = 0; t < 4; ++t)
      #pragma unroll
      for (int r = 0; r < 4; ++r)
        sv[t][r] = st[t][r] * c1 + (float)mk[t][r];
    float nm = sv[0][0];
    #pragma unroll
    for (int t = 0; t < 4; ++t)
      #pragma unroll
      for (int r = 0; r < 4; ++r) nm = fmaxf(nm, sv[t][r]);
    nm = fmaxf(nm, __shfl_xor(nm, 16));
    nm = fmaxf(nm, __shfl_xor(nm, 32));
    if (__any(nm > mrow + THR)) {
      float newm = fmaxf(mrow, nm);
      float f = __builtin_amdgcn_exp2f(mrow - newm);
      mrow = newm;
      ssum *= f;
      #pragma unroll
      for (int dt = 0; dt < 4; ++dt)
        #pragma unroll
        for (int r = 0; r < 4; ++r) acc[dt][r] *= f;
    }
    float p[4][4];
    float ps = 0.f;
    #pragma unroll
    for (int t = 0; t < 4; ++t)
      #pragma unroll
      for (int r = 0; r < 4; ++r) {
        p[t][r] = __builtin_amdgcn_exp2f(sv[t][r] - mrow);
        ps += p[t][r];
      }
    ps += __shfl_xor(ps, 16);
    ps += __shfl_xor(ps, 32);
    ssum += ps;
    #pragma unroll
    for (int t = 0; t < 4; ++t)
      #pragma unroll
      for (int hh = 0; hh < 2; ++hh) {
        union { bf16x2 v; unsigned int u; } pk;
        pk.v[0] = (bf16)p[t][2 * hh];
        pk.v[1] = (bf16)p[t][2 * hh + 1];
        Pu[w][lr][8 * t + 2 * lg + hh] = pk.u;
      }
    const bf16x8 pf0 = *(const bf16x8*)&Pu[w][lr][4 * lg];
    const bf16x8 pf1 = *(const bf16x8*)&Pu[w][lr][16 + 4 * lg];
    __builtin_amdgcn_s_setprio(1);
    #pragma unroll
    for (int dt = 0; dt < 4; ++dt) {
      bf16x8 vb0 = *(const bf16x8*)(Vc + (dt * 16 + lr) * 64 + ((lg ^ r7) * 8));
      acc[dt] = __builtin_amdgcn_mfma_f32_16x16x32_bf16(vb0, pf0, acc[dt], 0, 0, 0);
    }
    #pragma unroll
    for (int dt = 0; dt < 4; ++dt) {
      bf16x8 vb1 = *(const bf16x8*)(Vc + (dt * 16 + lr) * 64 + (((4 + lg) ^ r7) * 8));
      acc[dt] = __builtin_amdgcn_mfma_f32_16x16x32_bf16(vb1, pf1, acc[dt], 0, 0, 0);
    }
    __builtin_amdgcn_s_setprio(0);
    if (it < 15) {
      #pragma unroll
      for (int t = 0; t < 4; ++t) mk[t] = mkn[t];
    }
    __syncthreads();                  // drains prefetch (next tile ready), frees cur
    cur ^= 1;
  }
  // --- normalize + direct bf16 ctx write (lane owns q-row = lr) -------------
  const float inv = 1.f / ssum;
  bf16* cp = Ctx + ((size_t)(b * S_ + q0 + lr)) * H_ + h * DH_;
  #pragma unroll
  for (int dt = 0; dt < 4; ++dt) {
    bf16x4 o;
    #pragma unroll
    for (int r = 0; r < 4; ++r) o[r] = (bf16)(acc[dt][r] * inv);
    *(bf16x4*)(cp + dt * 16 + lg * 4) = o;
  }
}

// ---------------- launcher ----------------------------------------------------
extern "C" void kernel_launch(void* const* d_in, const int* in_sizes, int n_in,
                              void* d_out, int out_size, void* d_ws, size_t ws_size,
                              hipStream_t stream) {
  (void)in_sizes; (void)n_in; (void)out_size; (void)ws_size;
  const float* x    = (const float*)d_in[0];
  const float* mask = (const float*)d_in[1];
  const float* wq   = (const float*)d_in[2];
  const float* bq   = (const float*)d_in[3];
  const float* wk   = (const float*)d_in[4];
  const float* bk   = (const float*)d_in[5];
  const float* wv   = (const float*)d_in[6];
  const float* bv   = (const float*)d_in[7];
  const float* wo   = (const float*)d_in[8];
  const float* bo   = (const float*)d_in[9];
  const float* aat  = (const float*)d_in[10];
  const float* wi   = (const float*)d_in[11];
  const float* bi   = (const float*)d_in[12];
  const float* wf   = (const float*)d_in[13];
  const float* bf_  = (const float*)d_in[14];
  const float* afn  = (const float*)d_in[15];

  char* ws = (char*)d_ws;
  size_t o = 0;
  bf16* WtQKV = (bf16*)(ws + o); o += (size_t)L_ * 3 * H_ * H_ * 2; // 24MB
  bf16* WtO = (bf16*)(ws + o); o += (size_t)L_ * H_ * H_ * 2;       //  8MB
  bf16* WtI = (bf16*)(ws + o); o += (size_t)L_ * H_ * F_ * 2;       // 32MB
  bf16* WtF = (bf16*)(ws + o); o += (size_t)L_ * F_ * H_ * 2;       // 32MB
  bf16* madd = (bf16*)(ws + o); o += (size_t)B_ * S_ * S_ * 2;      //  4MB
  bf16* xb  = (bf16*)(ws + o); o += (size_t)M_ * H_ * 2;            //  4MB
  bf16* qb  = (bf16*)(ws + o); o += (size_t)M_ * H_ * 2;
  bf16* kbf = (bf16*)(ws + o); o += (size_t)M_ * H_ * 2;
  bf16* vt  = (bf16*)(ws + o); o += (size_t)M_ * H_ * 2;
  bf16* ctx = (bf16*)(ws + o); o += (size_t)M_ * H_ * 2;
  bf16* itm = (bf16*)(ws + o); o += (size_t)M_ * F_ * 2;            // 16MB
  float* part = (float*)(ws + o); o += (size_t)4 * M_ * H_ * 4;     // 32MB

  float* xf = (float*)d_out;  // running x lives in d_out (fp32)

  const size_t HH = (size_t)H_ * H_;
  transpose_all<<<dim3(49152), dim3(32, 8), 0, stream>>>(
      wq, wk, wv, wo, wi, wf, WtQKV, WtO, WtI, WtF);
  prep_kernel<<<dim3(4096), 256, 0, stream>>>(
      (const float4*)mask, (bf16x4*)madd, (const float4*)x, (float4*)xf,
      (bf16x4*)xb);

  for (int l = 0; l < L_; ++l) {
    gemm_qkv64<<<dim3(48, M_/128), 256, 0, stream>>>(
        xb, WtQKV + (size_t)l * 3 * HH,
        bq + l * H_, bk + l * H_, bv + l * H_, qb, kbf, vt);
    attn_kernel7<<<dim3(S_/64, NH_, B_), 256, 0, stream>>>(
        qb, kbf, vt, madd, ctx);
    gemm128_kernel<3><<<dim3(H_/128, M_/128, 4), 256, 0, stream>>>(
        ctx, WtO + (size_t)l * HH, nullptr, nullptr, part, H_, H_, H_ / 4);
    reduce_residual<<<dim3((M_ * H_ / 4) / 256), 256, 0, stream>>>(
        (const float4*)part, bo + l * H_, aat + l, (float4*)xf, (bf16x4*)xb);
    gemm128_kernel<1><<<dim3(F_/128, M_/128), 256, 0, stream>>>(
        xb, WtI + (size_t)l * H_ * F_, bi + l * F_, itm, nullptr, F_, H_, H_);
    gemm128_kernel<3><<<dim3(H_/128, M_/128, 4), 256, 0, stream>>>(
        itm, WtF + (size_t)l * F_ * H_, nullptr, nullptr, part, H_, F_, F_ / 4);
    reduce_residual<<<dim3((M_ * H_ / 4) / 256), 256, 0, stream>>>(
        (const float4*)part, bf_ + l * H_, afn + l, (float4*)xf, (bf16x4*)xb);
  }
}

// Round 9
// 606.513 us; speedup vs baseline: 1.6702x; 1.0415x over previous
//
#include <hip/hip_runtime.h>
#include <cstdint>

#define B_  2
#define S_  1024
#define H_  1024
#define NH_ 16
#define DH_ 64
#define F_  4096
#define L_  4
#define M_  (B_*S_)        // 2048 rows in all GEMMs

typedef __bf16 bf16;
typedef __bf16 bf16x8 __attribute__((ext_vector_type(8)));
typedef __bf16 bf16x4 __attribute__((ext_vector_type(4)));
typedef __bf16 bf16x2 __attribute__((ext_vector_type(2)));
typedef float  f32x4  __attribute__((ext_vector_type(4)));

// ---------------- async global->LDS (16B per lane), CK-style addrspace cast ----
__device__ __forceinline__ void async_ld16(void* lds, const void* g) {
  auto* lp = reinterpret_cast<__attribute__((address_space(3))) unsigned int*>(
      reinterpret_cast<uintptr_t>(lds));
  const auto* gp = reinterpret_cast<const __attribute__((address_space(1))) unsigned int*>(
      reinterpret_cast<uintptr_t>(g));
  __builtin_amdgcn_global_load_lds(gp, lp, 16, 0, 0);
}

__device__ __forceinline__ float gelu_tanh(float x) {
  float u = 0.7978845608028654f * (x + 0.044715f * x * x * x);
  u = fminf(fmaxf(u, -15.f), 15.f);
  float e = __builtin_amdgcn_exp2f(u * 2.8853900817779268f); // exp(2u)
  return 0.5f * x * (1.f + (e - 1.f) / (e + 1.f));
}

// ---------------- fused weight transpose+cvt v2: 64x64 tiles, coalesced -------
// 12288 blocks of (32,8). Segments: [0,4096) wq/wk/wv/wo; [4096,8192) wi;
// [8192,12288) wf. Reads float2 (256B/row), writes bf16x2 (128B segments).
__global__ __launch_bounds__(256) void transpose_all(
    const float* __restrict__ wq, const float* __restrict__ wk,
    const float* __restrict__ wv, const float* __restrict__ wo,
    const float* __restrict__ wi, const float* __restrict__ wf,
    bf16* __restrict__ WtQKV, bf16* __restrict__ WtO,
    bf16* __restrict__ WtI, bf16* __restrict__ WtF) {
  const size_t HH = (size_t)H_ * H_;
  const size_t HF = (size_t)H_ * F_;
  int idx = blockIdx.x;
  const float* src;
  bf16* dst;
  int N, K, k0, n0;
  if (idx < 4096) {
    const int s = idx >> 10;                       // wq/wk/wv/wo
    const int l = (idx >> 8) & 3;
    const int t = idx & 255;
    n0 = (t & 15) * 64; k0 = (t >> 4) * 64;
    N = H_; K = H_;
    src = (s == 0 ? wq : s == 1 ? wk : s == 2 ? wv : wo) + (size_t)l * HH;
    dst = (s < 3) ? (WtQKV + (size_t)l * 3 * HH + (size_t)s * HH)
                  : (WtO + (size_t)l * HH);
  } else if (idx < 8192) {
    const int j = idx - 4096;                      // wi [1024][4096]
    const int l = j >> 10;
    const int t = j & 1023;
    n0 = (t & 63) * 64; k0 = (t >> 6) * 64;
    N = F_; K = H_;
    src = wi + (size_t)l * HF;
    dst = WtI + (size_t)l * HF;
  } else {
    const int j = idx - 8192;                      // wf [4096][1024]
    const int l = j >> 10;
    const int t = j & 1023;
    n0 = (t & 15) * 64; k0 = (t >> 4) * 64;
    N = H_; K = F_;
    src = wf + (size_t)l * HF;
    dst = WtF + (size_t)l * HF;
  }
  __shared__ float t[64][65];
  const int x = threadIdx.x, y = threadIdx.y;
  // read 64 k-rows x 64 n-cols; store transposed t[n][k]
  #pragma unroll
  for (int i = 0; i < 64; i += 8) {
    const float2 v = *(const float2*)(src + (size_t)(k0 + y + i) * N + n0 + 2 * x);
    t[2 * x][y + i] = v.x;
    t[2 * x + 1][y + i] = v.y;
  }
  __syncthreads();
  #pragma unroll
  for (int i = 0; i < 64; i += 8) {
    bf16x2 o;
    o[0] = (bf16)t[y + i][2 * x];
    o[1] = (bf16)t[y + i][2 * x + 1];
    *(bf16x2*)(dst + (size_t)(n0 + y + i) * K + k0 + 2 * x) = o;
  }
}

// ---------------- fused prep: mask->bf16 log2 adder + x init ------------------
__global__ __launch_bounds__(256) void prep_kernel(
    const float4* __restrict__ mask, bf16x4* __restrict__ madd,
    const float4* __restrict__ x, float4* __restrict__ xf,
    bf16x4* __restrict__ xb) {
  const int blk = blockIdx.x;
  if (blk < 2048) {
    const int i = blk * 256 + (int)threadIdx.x;
    const float c2 = -10000.f * 1.44269504088896f;
    float4 v = mask[i];
    bf16x4 o;
    o[0] = (bf16)((1.f - v.x) * c2);
    o[1] = (bf16)((1.f - v.y) * c2);
    o[2] = (bf16)((1.f - v.z) * c2);
    o[3] = (bf16)((1.f - v.w) * c2);
    madd[i] = o;
  } else {
    const int i = (blk - 2048) * 256 + (int)threadIdx.x;
    float4 v = x[i];
    xf[i] = v;
    bf16x4 b;
    b[0] = (bf16)v.x; b[1] = (bf16)v.y; b[2] = (bf16)v.z; b[3] = (bf16)v.w;
    xb[i] = b;
  }
}

// ---------------- double-buffered GEMM core: C[128x128] = A[.][ld] @ Bt[.][ld]^T
__device__ __forceinline__ void gemm_core(
    const bf16* __restrict__ A, const bf16* __restrict__ Bt, int ld, int kLen,
    int m0, int n0, bf16* As, bf16* Bs, f32x4 (&acc)[4][4]) {
  const int tid = (int)threadIdx.x;
  const int w = tid >> 6, l = tid & 63;
  const int lr = l & 15, lg = l >> 4;
  const int wm = w >> 1, wn = w & 1;
  const int srow = l >> 2;
  const int scol = (l & 3) * 8;

  const bf16* ag = A  + (size_t)(m0 + w * 32 + srow) * ld + scol;
  const bf16* bg = Bt + (size_t)(n0 + w * 32 + srow) * ld + scol;
  const int soff = (w * 32) * 32;

  auto stage = [&](int buf, int kk) {
    bf16* ad = As + buf * 4096 + soff;
    bf16* bd = Bs + buf * 4096 + soff;
    async_ld16(ad,           ag + kk);
    async_ld16(ad + 16 * 32, ag + kk + (size_t)16 * ld);
    async_ld16(bd,           bg + kk);
    async_ld16(bd + 16 * 32, bg + kk + (size_t)16 * ld);
  };

  stage(0, 0);
  __syncthreads();
  int cur = 0;
  for (int k0 = 0; k0 < kLen; k0 += 32) {
    if (k0 + 32 < kLen) stage(cur ^ 1, k0 + 32);
    const bf16* Ab = As + cur * 4096;
    const bf16* Bb = Bs + cur * 4096;
    bf16x8 af[4], bv[4];
    #pragma unroll
    for (int i = 0; i < 4; ++i)
      af[i] = *(const bf16x8*)(Ab + (wm * 64 + i * 16 + lr) * 32 + lg * 8);
    #pragma unroll
    for (int i = 0; i < 4; ++i)
      bv[i] = *(const bf16x8*)(Bb + (wn * 64 + i * 16 + lr) * 32 + lg * 8);
    #pragma unroll
    for (int i = 0; i < 4; ++i)
      #pragma unroll
      for (int j = 0; j < 4; ++j)
        acc[i][j] = __builtin_amdgcn_mfma_f32_16x16x32_bf16(af[i], bv[j], acc[i][j], 0, 0, 0);
    __syncthreads();
    cur ^= 1;
  }
}

// MODE 1: out_bf16 = gelu(acc+bias) | MODE 3: bf16 partial -> outb[z*M*N + idx]
template <int MODE>
__global__ __launch_bounds__(256) void gemm128_kernel(
    const bf16* __restrict__ A, const bf16* __restrict__ Bt,
    const float* __restrict__ bias, bf16* __restrict__ outb,
    int N, int K, int kSlice) {
  __shared__ __align__(16) bf16 As[2 * 128 * 32];
  __shared__ __align__(16) bf16 Bs[2 * 128 * 32];
  const int m0 = blockIdx.y * 128, n0 = blockIdx.x * 128;
  const int z = blockIdx.z;
  const f32x4 z4 = {0.f, 0.f, 0.f, 0.f};
  f32x4 acc[4][4];
  #pragma unroll
  for (int i = 0; i < 4; ++i)
    #pragma unroll
    for (int j = 0; j < 4; ++j) acc[i][j] = z4;

  gemm_core(A + (size_t)z * kSlice, Bt + (size_t)z * kSlice, K, kSlice,
            m0, n0, As, Bs, acc);

  const int tid = (int)threadIdx.x;
  const int w = tid >> 6, l = tid & 63;
  const int lr = l & 15, lg = l >> 4;
  const int wm = w >> 1, wn = w & 1;
  const size_t pbase = (MODE == 3) ? (size_t)z * M_ * (size_t)N : 0;
  #pragma unroll
  for (int i = 0; i < 4; ++i) {
    const int row0 = m0 + wm * 64 + i * 16 + lg * 4;
    #pragma unroll
    for (int j = 0; j < 4; ++j) {
      const int col = n0 + wn * 64 + j * 16 + lr;
      const float bvx = (MODE == 3) ? 0.f : bias[col];
      #pragma unroll
      for (int r = 0; r < 4; ++r) {
        const size_t idx = (size_t)(row0 + r) * N + col;
        float v = acc[i][j][r] + bvx;
        if (MODE == 3) {
          outb[pbase + idx] = (bf16)v;
        } else {
          outb[idx] = (bf16)gelu_tanh(v);
        }
      }
    }
  }
}

// ---------------- split-K reduce (bf16 partials, z=4) + bias + ReZero ---------
__global__ __launch_bounds__(256) void reduce_residual(
    const bf16x4* __restrict__ part, const float* __restrict__ bias,
    const float* __restrict__ alphap, float4* __restrict__ xf,
    bf16x4* __restrict__ xb) {
  const int i = blockIdx.x * 256 + (int)threadIdx.x;   // over M_*H_/4
  const int nper = M_ * H_ / 4;
  float s[4] = {0.f, 0.f, 0.f, 0.f};
  #pragma unroll
  for (int zz = 0; zz < 4; ++zz) {
    const bf16x4 p = part[i + (size_t)zz * nper];
    #pragma unroll
    for (int k = 0; k < 4; ++k) s[k] += (float)p[k];
  }
  const int col = (i * 4) & (H_ - 1);
  const float4 b4 = *(const float4*)(bias + col);
  const float a = *alphap;
  float4 xv = xf[i];
  xv.x += a * (s[0] + b4.x);
  xv.y += a * (s[1] + b4.y);
  xv.z += a * (s[2] + b4.z);
  xv.w += a * (s[3] + b4.w);
  xf[i] = xv;
  bf16x4 bb;
  bb[0] = (bf16)xv.x; bb[1] = (bf16)xv.y; bb[2] = (bf16)xv.z; bb[3] = (bf16)xv.w;
  xb[i] = bb;
}

// ---------------- QKV GEMM, BN=64 tile: grid (48, 16) = 768 blocks ------------
__global__ __launch_bounds__(256) void gemm_qkv64(
    const bf16* __restrict__ A, const bf16* __restrict__ Wt,
    const float* __restrict__ bq, const float* __restrict__ bk,
    const float* __restrict__ bvv,
    bf16* __restrict__ qo, bf16* __restrict__ ko, bf16* __restrict__ vt) {
  __shared__ __align__(16) bf16 As[2 * 128 * 32];
  __shared__ __align__(16) bf16 Bs[2 * 64 * 32];
  const int tid = (int)threadIdx.x;
  const int w = tid >> 6, l = tid & 63;
  const int lr = l & 15, lg = l >> 4;
  const int wm = w >> 1, wn = w & 1;
  const int srow = l >> 2, scol = (l & 3) * 8;
  const int m0 = blockIdx.y * 128, n0 = blockIdx.x * 64;

  const bf16* ag = A  + (size_t)(m0 + w * 32 + srow) * H_ + scol;
  const bf16* bg = Wt + (size_t)(n0 + w * 16 + srow) * H_ + scol;
  const int aoff = (w * 32) * 32;
  const int boff = (w * 16) * 32;

  auto stage = [&](int buf, int kk) {
    bf16* ad = As + buf * 4096 + aoff;
    bf16* bd = Bs + buf * 2048 + boff;
    async_ld16(ad,           ag + kk);
    async_ld16(ad + 16 * 32, ag + kk + (size_t)16 * H_);
    async_ld16(bd,           bg + kk);
  };

  const f32x4 z4 = {0.f, 0.f, 0.f, 0.f};
  f32x4 acc[4][2];
  #pragma unroll
  for (int i = 0; i < 4; ++i)
    #pragma unroll
    for (int j = 0; j < 2; ++j) acc[i][j] = z4;

  stage(0, 0);
  __syncthreads();
  int cur = 0;
  for (int k0 = 0; k0 < H_; k0 += 32) {
    if (k0 + 32 < H_) stage(cur ^ 1, k0 + 32);
    const bf16* Ab = As + cur * 4096;
    const bf16* Bb = Bs + cur * 2048;
    bf16x8 af[4], bv[2];
    #pragma unroll
    for (int i = 0; i < 4; ++i)
      af[i] = *(const bf16x8*)(Ab + (wm * 64 + i * 16 + lr) * 32 + lg * 8);
    #pragma unroll
    for (int j = 0; j < 2; ++j)
      bv[j] = *(const bf16x8*)(Bb + (wn * 32 + j * 16 + lr) * 32 + lg * 8);
    #pragma unroll
    for (int i = 0; i < 4; ++i)
      #pragma unroll
      for (int j = 0; j < 2; ++j)
        acc[i][j] = __builtin_amdgcn_mfma_f32_16x16x32_bf16(af[i], bv[j], acc[i][j], 0, 0, 0);
    __syncthreads();
    cur ^= 1;
  }

  if (n0 < 2048) {  // Q or K: direct [B,S,H] store
    bf16* out = (n0 < 1024) ? qo : ko;
    const float* bias = (n0 < 1024) ? bq : bk;
    const int nl = n0 & 1023;
    #pragma unroll
    for (int i = 0; i < 4; ++i) {
      const int row0 = m0 + wm * 64 + i * 16 + lg * 4;
      #pragma unroll
      for (int j = 0; j < 2; ++j) {
        const int col = nl + wn * 32 + j * 16 + lr;
        const float bvx = bias[col];
        #pragma unroll
        for (int r = 0; r < 4; ++r)
          out[(size_t)(row0 + r) * H_ + col] = (bf16)(acc[i][j][r] + bvx);
      }
    }
  } else {          // V: transposed store Vt[((b*NH+h)*DH+d)*S + s]
    const int hh = (n0 >> 6) - 32;
    #pragma unroll
    for (int i = 0; i < 4; ++i) {
      const int row0 = m0 + wm * 64 + i * 16 + lg * 4;
      const int bb = row0 >> 10, ss = row0 & (S_ - 1);
      #pragma unroll
      for (int j = 0; j < 2; ++j) {
        const int dd = wn * 32 + j * 16 + lr;
        const float bvx = bvv[hh * 64 + dd];
        bf16x4 pk;
        #pragma unroll
        for (int r = 0; r < 4; ++r) pk[r] = (bf16)(acc[i][j][r] + bvx);
        *(bf16x4*)(vt + (((size_t)(bb * NH_ + hh) * DH_ + dd) << 10) + ss) = pk;
      }
    }
  }
}

// ---------------- flash attention v7: LDS-staged K/V + mask reg-pipeline ------
__global__ __launch_bounds__(256) void attn_kernel7(
    const bf16* __restrict__ Q, const bf16* __restrict__ Kb,
    const bf16* __restrict__ Vt, const bf16* __restrict__ madd,
    bf16* __restrict__ Ctx) {
  const int tid = (int)threadIdx.x;
  const int w = tid >> 6, l = tid & 63;
  const int lr = l & 15, lg = l >> 4;
  const int r7 = lr & 7;
  const int h = blockIdx.y, b = blockIdx.z;
  const int q0 = blockIdx.x * 64 + w * 16;

  __shared__ __align__(16) bf16 Kt[2][64 * 64];  // [buf][kv][d] swizzled
  __shared__ __align__(16) bf16 Vs[2][64 * 64];  // [buf][d][kv] swizzled
  __shared__ unsigned int Pu[4][16][36];         // per-wave P, u32-packed bf16

  const bf16* qp = Q + ((size_t)(b * S_ + q0 + lr)) * H_ + h * DH_;
  const bf16x8 qa0 = *(const bf16x8*)(qp + lg * 8);
  const bf16x8 qa1 = *(const bf16x8*)(qp + 32 + lg * 8);

  const f32x4 z4 = {0.f, 0.f, 0.f, 0.f};
  f32x4 acc[4];
  #pragma unroll
  for (int dt = 0; dt < 4; ++dt) acc[dt] = z4;
  float mrow = -1e30f, ssum = 0.f;

  const bf16* Kbase = Kb + ((size_t)b * S_) * H_ + h * DH_;
  const bf16* Vbase = Vt + ((size_t)(b * NH_ + h)) * DH_ * S_;
  const bf16* Mb = madd + ((size_t)(b * S_ + q0 + lr)) * S_;

  const float c1 = 0.125f * 1.44269504088896f;   // scale * log2(e)
  const float THR = 10.f;                        // defer-max headroom (base-2)

  const int sub = l >> 3;
  const int cs  = ((l & 7) ^ sub) * 8;
  auto stage = [&](int buf, int kv) {
    #pragma unroll
    for (int j = 0; j < 2; ++j) {
      const int rbase = w * 16 + j * 8;
      async_ld16(&Kt[buf][rbase * 64],
                 Kbase + (size_t)(kv + rbase + sub) * H_ + cs);
      async_ld16(&Vs[buf][rbase * 64],
                 Vbase + (size_t)(rbase + sub) * S_ + kv + cs);
    }
  };

  stage(0, 0);
  bf16x4 mk[4];
  #pragma unroll
  for (int t = 0; t < 4; ++t) mk[t] = *(const bf16x4*)(Mb + t * 16 + lg * 4);
  __syncthreads();                    // vmcnt(0) drain: tile 0 ready
  int cur = 0;
  #pragma unroll 1
  for (int it = 0; it < 16; ++it) {
    const int kv0 = it * 64;
    if (it < 15) stage(cur ^ 1, kv0 + 64);   // async prefetch next K/V tile
    bf16x4 mkn[4];
    if (it < 15) {
      #pragma unroll
      for (int t = 0; t < 4; ++t)
        mkn[t] = *(const bf16x4*)(Mb + kv0 + 64 + t * 16 + lg * 4);
    }
    const bf16* Kc = &Kt[cur][0];
    const bf16* Vc = &Vs[cur][0];
    bf16x8 kf0[4], kf1[4];
    #pragma unroll
    for (int t = 0; t < 4; ++t) {
      kf0[t] = *(const bf16x8*)(Kc + (t * 16 + lr) * 64 + ((lg ^ r7) * 8));
      kf1[t] = *(const bf16x8*)(Kc + (t * 16 + lr) * 64 + (((4 + lg) ^ r7) * 8));
    }
    f32x4 st[4];
    __builtin_amdgcn_s_setprio(1);
    #pragma unroll
    for (int t = 0; t < 4; ++t) {
      f32x4 s = __builtin_amdgcn_mfma_f32_16x16x32_bf16(kf0[t], qa0, z4, 0, 0, 0);
      st[t] = __builtin_amdgcn_mfma_f32_16x16x32_bf16(kf1[t], qa1, s, 0, 0, 0);
    }
    __builtin_amdgcn_s_setprio(0);
    float sv[4][4];
    #pragma unroll
    for (int t = 0; t < 4; ++t)
      #pragma unroll
      for (int r = 0; r < 4; ++r)
        sv[t][r] = st[t][r] * c1 + (float)mk[t][r];
    float nm = sv[0][0];
    #pragma unroll
    for (int t = 0; t < 4; ++t)
      #pragma unroll
      for (int r = 0; r < 4; ++r) nm = fmaxf(nm, sv[t][r]);
    nm = fmaxf(nm, __shfl_xor(nm, 16));
    nm = fmaxf(nm, __shfl_xor(nm, 32));
    if (__any(nm > mrow + THR)) {
      float newm = fmaxf(mrow, nm);
      float f = __builtin_amdgcn_exp2f(mrow - newm);
      mrow = newm;
      ssum *= f;
      #pragma unroll
      for (int dt = 0; dt < 4; ++dt)
        #pragma unroll
        for (int r = 0; r < 4; ++r) acc[dt][r] *= f;
    }
    float p[4][4];
    float ps = 0.f;
    #pragma unroll
    for (int t = 0; t < 4; ++t)
      #pragma unroll
      for (int r = 0; r < 4; ++r) {
        p[t][r] = __builtin_amdgcn_exp2f(sv[t][r] - mrow);
        ps += p[t][r];
      }
    ps += __shfl_xor(ps, 16);
    ps += __shfl_xor(ps, 32);
    ssum += ps;
    #pragma unroll
    for (int t = 0; t < 4; ++t)
      #pragma unroll
      for (int hh = 0; hh < 2; ++hh) {
        union { bf16x2 v; unsigned int u; } pk;
        pk.v[0] = (bf16)p[t][2 * hh];
        pk.v[1] = (bf16)p[t][2 * hh + 1];
        Pu[w][lr][8 * t + 2 * lg + hh] = pk.u;
      }
    const bf16x8 pf0 = *(const bf16x8*)&Pu[w][lr][4 * lg];
    const bf16x8 pf1 = *(const bf16x8*)&Pu[w][lr][16 + 4 * lg];
    __builtin_amdgcn_s_setprio(1);
    #pragma unroll
    for (int dt = 0; dt < 4; ++dt) {
      bf16x8 vb0 = *(const bf16x8*)(Vc + (dt * 16 + lr) * 64 + ((lg ^ r7) * 8));
      acc[dt] = __builtin_amdgcn_mfma_f32_16x16x32_bf16(vb0, pf0, acc[dt], 0, 0, 0);
    }
    #pragma unroll
    for (int dt = 0; dt < 4; ++dt) {
      bf16x8 vb1 = *(const bf16x8*)(Vc + (dt * 16 + lr) * 64 + (((4 + lg) ^ r7) * 8));
      acc[dt] = __builtin_amdgcn_mfma_f32_16x16x32_bf16(vb1, pf1, acc[dt], 0, 0, 0);
    }
    __builtin_amdgcn_s_setprio(0);
    if (it < 15) {
      #pragma unroll
      for (int t = 0; t < 4; ++t) mk[t] = mkn[t];
    }
    __syncthreads();                  // drains prefetch (next tile ready), frees cur
    cur ^= 1;
  }
  const float inv = 1.f / ssum;
  bf16* cp = Ctx + ((size_t)(b * S_ + q0 + lr)) * H_ + h * DH_;
  #pragma unroll
  for (int dt = 0; dt < 4; ++dt) {
    bf16x4 o;
    #pragma unroll
    for (int r = 0; r < 4; ++r) o[r] = (bf16)(acc[dt][r] * inv);
    *(bf16x4*)(cp + dt * 16 + lg * 4) = o;
  }
}

// ---------------- launcher ----------------------------------------------------
extern "C" void kernel_launch(void* const* d_in, const int* in_sizes, int n_in,
                              void* d_out, int out_size, void* d_ws, size_t ws_size,
                              hipStream_t stream) {
  (void)in_sizes; (void)n_in; (void)out_size; (void)ws_size;
  const float* x    = (const float*)d_in[0];
  const float* mask = (const float*)d_in[1];
  const float* wq   = (const float*)d_in[2];
  const float* bq   = (const float*)d_in[3];
  const float* wk   = (const float*)d_in[4];
  const float* bk   = (const float*)d_in[5];
  const float* wv   = (const float*)d_in[6];
  const float* bv   = (const float*)d_in[7];
  const float* wo   = (const float*)d_in[8];
  const float* bo   = (const float*)d_in[9];
  const float* aat  = (const float*)d_in[10];
  const float* wi   = (const float*)d_in[11];
  const float* bi   = (const float*)d_in[12];
  const float* wf   = (const float*)d_in[13];
  const float* bf_  = (const float*)d_in[14];
  const float* afn  = (const float*)d_in[15];

  char* ws = (char*)d_ws;
  size_t o = 0;
  bf16* WtQKV = (bf16*)(ws + o); o += (size_t)L_ * 3 * H_ * H_ * 2; // 24MB
  bf16* WtO = (bf16*)(ws + o); o += (size_t)L_ * H_ * H_ * 2;       //  8MB
  bf16* WtI = (bf16*)(ws + o); o += (size_t)L_ * H_ * F_ * 2;       // 32MB
  bf16* WtF = (bf16*)(ws + o); o += (size_t)L_ * F_ * H_ * 2;       // 32MB
  bf16* madd = (bf16*)(ws + o); o += (size_t)B_ * S_ * S_ * 2;      //  4MB
  bf16* xb  = (bf16*)(ws + o); o += (size_t)M_ * H_ * 2;            //  4MB
  bf16* qb  = (bf16*)(ws + o); o += (size_t)M_ * H_ * 2;
  bf16* kbf = (bf16*)(ws + o); o += (size_t)M_ * H_ * 2;
  bf16* vt  = (bf16*)(ws + o); o += (size_t)M_ * H_ * 2;
  bf16* ctx = (bf16*)(ws + o); o += (size_t)M_ * H_ * 2;
  bf16* itm = (bf16*)(ws + o); o += (size_t)M_ * F_ * 2;            // 16MB
  bf16* partb = (bf16*)(ws + o); o += (size_t)4 * M_ * H_ * 2;      // 16MB

  float* xf = (float*)d_out;  // running x lives in d_out (fp32)

  const size_t HH = (size_t)H_ * H_;
  transpose_all<<<dim3(12288), dim3(32, 8), 0, stream>>>(
      wq, wk, wv, wo, wi, wf, WtQKV, WtO, WtI, WtF);
  prep_kernel<<<dim3(4096), 256, 0, stream>>>(
      (const float4*)mask, (bf16x4*)madd, (const float4*)x, (float4*)xf,
      (bf16x4*)xb);

  for (int l = 0; l < L_; ++l) {
    gemm_qkv64<<<dim3(48, M_/128), 256, 0, stream>>>(
        xb, WtQKV + (size_t)l * 3 * HH,
        bq + l * H_, bk + l * H_, bv + l * H_, qb, kbf, vt);
    attn_kernel7<<<dim3(S_/64, NH_, B_), 256, 0, stream>>>(
        qb, kbf, vt, madd, ctx);
    gemm128_kernel<3><<<dim3(H_/128, M_/128, 4), 256, 0, stream>>>(
        ctx, WtO + (size_t)l * HH, nullptr, partb, H_, H_, H_ / 4);
    reduce_residual<<<dim3((M_ * H_ / 4) / 256), 256, 0, stream>>>(
        (const bf16x4*)partb, bo + l * H_, aat + l, (float4*)xf, (bf16x4*)xb);
    gemm128_kernel<1><<<dim3(F_/128, M_/128), 256, 0, stream>>>(
        xb, WtI + (size_t)l * H_ * F_, bi + l * F_, itm, F_, H_, H_);
    gemm128_kernel<3><<<dim3(H_/128, M_/128, 4), 256, 0, stream>>>(
        itm, WtF + (size_t)l * F_ * H_, nullptr, partb, H_, F_, F_ / 4);
    reduce_residual<<<dim3((M_ * H_ / 4) / 256), 256, 0, stream>>>(
        (const bf16x4*)partb, bf_ + l * H_, afn + l, (float4*)xf, (bf16x4*)xb);
  }
}

// Round 10
// 602.989 us; speedup vs baseline: 1.6799x; 1.0058x over previous
//
#include <hip/hip_runtime.h>
#include <cstdint>

#define B_  2
#define S_  1024
#define H_  1024
#define NH_ 16
#define DH_ 64
#define F_  4096
#define L_  4
#define M_  (B_*S_)        // 2048 rows in all GEMMs

typedef __bf16 bf16;
typedef __bf16 bf16x8 __attribute__((ext_vector_type(8)));
typedef __bf16 bf16x4 __attribute__((ext_vector_type(4)));
typedef __bf16 bf16x2 __attribute__((ext_vector_type(2)));
typedef float  f32x4  __attribute__((ext_vector_type(4)));

// ---------------- async global->LDS (16B per lane), CK-style addrspace cast ----
__device__ __forceinline__ void async_ld16(void* lds, const void* g) {
  auto* lp = reinterpret_cast<__attribute__((address_space(3))) unsigned int*>(
      reinterpret_cast<uintptr_t>(lds));
  const auto* gp = reinterpret_cast<const __attribute__((address_space(1))) unsigned int*>(
      reinterpret_cast<uintptr_t>(g));
  __builtin_amdgcn_global_load_lds(gp, lp, 16, 0, 0);
}

__device__ __forceinline__ float gelu_tanh(float x) {
  float u = 0.7978845608028654f * (x + 0.044715f * x * x * x);
  u = fminf(fmaxf(u, -15.f), 15.f);
  float e = __builtin_amdgcn_exp2f(u * 2.8853900817779268f); // exp(2u)
  return 0.5f * x * (1.f + (e - 1.f) / (e + 1.f));
}

// ---------------- fused weight transpose+cvt v3: 512K x 32N tiles --------------
// Write-side optimized: each output row is a 1KB contiguous bf16 stream
// (reads are L3-resident per round-9 FETCH_SIZE evidence; writes are the HBM
// traffic that matters). 3072 blocks x 256 threads.
// Segments: [0,1024) wq/wk/wv/wo; [1024,2048) wi; [2048,3072) wf.
__global__ __launch_bounds__(256) void transpose_all(
    const float* __restrict__ wq, const float* __restrict__ wk,
    const float* __restrict__ wv, const float* __restrict__ wo,
    const float* __restrict__ wi, const float* __restrict__ wf,
    bf16* __restrict__ WtQKV, bf16* __restrict__ WtO,
    bf16* __restrict__ WtI, bf16* __restrict__ WtF) {
  const size_t HH = (size_t)H_ * H_;
  const size_t HF = (size_t)H_ * F_;
  int idx = blockIdx.x;
  const float* src;
  bf16* dst;
  int N, K, kk0, n0;
  if (idx < 1024) {
    const int mat = idx >> 6;            // 0..15: 4 weights x 4 layers
    const int s = mat >> 2, l = mat & 3;
    const int t = idx & 63;              // 2 kt x 32 nt
    kk0 = (t >> 5) * 512; n0 = (t & 31) * 32;
    N = H_; K = H_;
    src = (s == 0 ? wq : s == 1 ? wk : s == 2 ? wv : wo) + (size_t)l * HH;
    dst = (s < 3) ? (WtQKV + (size_t)l * 3 * HH + (size_t)s * HH)
                  : (WtO + (size_t)l * HH);
  } else if (idx < 2048) {
    const int j = idx - 1024;            // wi [1024][4096]: 2 kt x 128 nt
    const int l = j >> 8;
    const int t = j & 255;
    kk0 = (t >> 7) * 512; n0 = (t & 127) * 32;
    N = F_; K = H_;
    src = wi + (size_t)l * HF;
    dst = WtI + (size_t)l * HF;
  } else {
    const int j = idx - 2048;            // wf [4096][1024]: 8 kt x 32 nt
    const int l = j >> 8;
    const int t = j & 255;
    kk0 = (t >> 5) * 512; n0 = (t & 31) * 32;
    N = H_; K = F_;
    src = wf + (size_t)l * HF;
    dst = WtF + (size_t)l * HF;
  }
  __shared__ __align__(16) bf16 t[32][520];   // [n][k], pad 520 (row = 1040B, 16B-mult)
  const int tid = (int)threadIdx.x;
  const int r = tid >> 3, c = tid & 7;        // read: 32 k-rows/pass, 8 float4/row
  #pragma unroll
  for (int p = 0; p < 16; ++p) {
    const int k = p * 32 + r;
    const float4 v = *(const float4*)(src + (size_t)(kk0 + k) * N + n0 + c * 4);
    t[c * 4 + 0][k] = (bf16)v.x;
    t[c * 4 + 1][k] = (bf16)v.y;
    t[c * 4 + 2][k] = (bf16)v.z;
    t[c * 4 + 3][k] = (bf16)v.w;
  }
  __syncthreads();
  const int ln = tid & 63, wv_ = tid >> 6;    // write: 4 n-rows/pass, 1KB/row
  #pragma unroll
  for (int p = 0; p < 8; ++p) {
    const int n = p * 4 + wv_;
    *(bf16x8*)(dst + (size_t)(n0 + n) * K + kk0 + ln * 8) =
        *(const bf16x8*)&t[n][ln * 8];
  }
}

// ---------------- fused prep: mask->bf16 log2 adder + x init ------------------
__global__ __launch_bounds__(256) void prep_kernel(
    const float4* __restrict__ mask, bf16x4* __restrict__ madd,
    const float4* __restrict__ x, float4* __restrict__ xf,
    bf16x4* __restrict__ xb) {
  const int blk = blockIdx.x;
  if (blk < 2048) {
    const int i = blk * 256 + (int)threadIdx.x;
    const float c2 = -10000.f * 1.44269504088896f;
    float4 v = mask[i];
    bf16x4 o;
    o[0] = (bf16)((1.f - v.x) * c2);
    o[1] = (bf16)((1.f - v.y) * c2);
    o[2] = (bf16)((1.f - v.z) * c2);
    o[3] = (bf16)((1.f - v.w) * c2);
    madd[i] = o;
  } else {
    const int i = (blk - 2048) * 256 + (int)threadIdx.x;
    float4 v = x[i];
    xf[i] = v;
    bf16x4 b;
    b[0] = (bf16)v.x; b[1] = (bf16)v.y; b[2] = (bf16)v.z; b[3] = (bf16)v.w;
    xb[i] = b;
  }
}

// ---------------- double-buffered GEMM core: C[128x128] = A[.][ld] @ Bt[.][ld]^T
__device__ __forceinline__ void gemm_core(
    const bf16* __restrict__ A, const bf16* __restrict__ Bt, int ld, int kLen,
    int m0, int n0, bf16* As, bf16* Bs, f32x4 (&acc)[4][4]) {
  const int tid = (int)threadIdx.x;
  const int w = tid >> 6, l = tid & 63;
  const int lr = l & 15, lg = l >> 4;
  const int wm = w >> 1, wn = w & 1;
  const int srow = l >> 2;
  const int scol = (l & 3) * 8;

  const bf16* ag = A  + (size_t)(m0 + w * 32 + srow) * ld + scol;
  const bf16* bg = Bt + (size_t)(n0 + w * 32 + srow) * ld + scol;
  const int soff = (w * 32) * 32;

  auto stage = [&](int buf, int kk) {
    bf16* ad = As + buf * 4096 + soff;
    bf16* bd = Bs + buf * 4096 + soff;
    async_ld16(ad,           ag + kk);
    async_ld16(ad + 16 * 32, ag + kk + (size_t)16 * ld);
    async_ld16(bd,           bg + kk);
    async_ld16(bd + 16 * 32, bg + kk + (size_t)16 * ld);
  };

  stage(0, 0);
  __syncthreads();
  int cur = 0;
  for (int k0 = 0; k0 < kLen; k0 += 32) {
    if (k0 + 32 < kLen) stage(cur ^ 1, k0 + 32);
    const bf16* Ab = As + cur * 4096;
    const bf16* Bb = Bs + cur * 4096;
    bf16x8 af[4], bv[4];
    #pragma unroll
    for (int i = 0; i < 4; ++i)
      af[i] = *(const bf16x8*)(Ab + (wm * 64 + i * 16 + lr) * 32 + lg * 8);
    #pragma unroll
    for (int i = 0; i < 4; ++i)
      bv[i] = *(const bf16x8*)(Bb + (wn * 64 + i * 16 + lr) * 32 + lg * 8);
    #pragma unroll
    for (int i = 0; i < 4; ++i)
      #pragma unroll
      for (int j = 0; j < 4; ++j)
        acc[i][j] = __builtin_amdgcn_mfma_f32_16x16x32_bf16(af[i], bv[j], acc[i][j], 0, 0, 0);
    __syncthreads();
    cur ^= 1;
  }
}

// MODE 1: out_bf16 = gelu(acc+bias) | MODE 3: bf16 partial -> outb[z*M*N + idx]
template <int MODE>
__global__ __launch_bounds__(256) void gemm128_kernel(
    const bf16* __restrict__ A, const bf16* __restrict__ Bt,
    const float* __restrict__ bias, bf16* __restrict__ outb,
    int N, int K, int kSlice) {
  __shared__ __align__(16) bf16 As[2 * 128 * 32];
  __shared__ __align__(16) bf16 Bs[2 * 128 * 32];
  const int m0 = blockIdx.y * 128, n0 = blockIdx.x * 128;
  const int z = blockIdx.z;
  const f32x4 z4 = {0.f, 0.f, 0.f, 0.f};
  f32x4 acc[4][4];
  #pragma unroll
  for (int i = 0; i < 4; ++i)
    #pragma unroll
    for (int j = 0; j < 4; ++j) acc[i][j] = z4;

  gemm_core(A + (size_t)z * kSlice, Bt + (size_t)z * kSlice, K, kSlice,
            m0, n0, As, Bs, acc);

  const int tid = (int)threadIdx.x;
  const int w = tid >> 6, l = tid & 63;
  const int lr = l & 15, lg = l >> 4;
  const int wm = w >> 1, wn = w & 1;
  const size_t pbase = (MODE == 3) ? (size_t)z * M_ * (size_t)N : 0;
  #pragma unroll
  for (int i = 0; i < 4; ++i) {
    const int row0 = m0 + wm * 64 + i * 16 + lg * 4;
    #pragma unroll
    for (int j = 0; j < 4; ++j) {
      const int col = n0 + wn * 64 + j * 16 + lr;
      const float bvx = (MODE == 3) ? 0.f : bias[col];
      #pragma unroll
      for (int r = 0; r < 4; ++r) {
        const size_t idx = (size_t)(row0 + r) * N + col;
        float v = acc[i][j][r] + bvx;
        if (MODE == 3) {
          outb[pbase + idx] = (bf16)v;
        } else {
          outb[idx] = (bf16)gelu_tanh(v);
        }
      }
    }
  }
}

// ---------------- split-K reduce (bf16 partials, z=4) + bias + ReZero ---------
__global__ __launch_bounds__(256) void reduce_residual(
    const bf16x4* __restrict__ part, const float* __restrict__ bias,
    const float* __restrict__ alphap, float4* __restrict__ xf,
    bf16x4* __restrict__ xb) {
  const int i = blockIdx.x * 256 + (int)threadIdx.x;   // over M_*H_/4
  const int nper = M_ * H_ / 4;
  float s[4] = {0.f, 0.f, 0.f, 0.f};
  #pragma unroll
  for (int zz = 0; zz < 4; ++zz) {
    const bf16x4 p = part[i + (size_t)zz * nper];
    #pragma unroll
    for (int k = 0; k < 4; ++k) s[k] += (float)p[k];
  }
  const int col = (i * 4) & (H_ - 1);
  const float4 b4 = *(const float4*)(bias + col);
  const float a = *alphap;
  float4 xv = xf[i];
  xv.x += a * (s[0] + b4.x);
  xv.y += a * (s[1] + b4.y);
  xv.z += a * (s[2] + b4.z);
  xv.w += a * (s[3] + b4.w);
  xf[i] = xv;
  bf16x4 bb;
  bb[0] = (bf16)xv.x; bb[1] = (bf16)xv.y; bb[2] = (bf16)xv.z; bb[3] = (bf16)xv.w;
  xb[i] = bb;
}

// ---------------- QKV GEMM, BN=64 tile: grid (48, 16) = 768 blocks ------------
__global__ __launch_bounds__(256) void gemm_qkv64(
    const bf16* __restrict__ A, const bf16* __restrict__ Wt,
    const float* __restrict__ bq, const float* __restrict__ bk,
    const float* __restrict__ bvv,
    bf16* __restrict__ qo, bf16* __restrict__ ko, bf16* __restrict__ vt) {
  __shared__ __align__(16) bf16 As[2 * 128 * 32];
  __shared__ __align__(16) bf16 Bs[2 * 64 * 32];
  const int tid = (int)threadIdx.x;
  const int w = tid >> 6, l = tid & 63;
  const int lr = l & 15, lg = l >> 4;
  const int wm = w >> 1, wn = w & 1;
  const int srow = l >> 2, scol = (l & 3) * 8;
  const int m0 = blockIdx.y * 128, n0 = blockIdx.x * 64;

  const bf16* ag = A  + (size_t)(m0 + w * 32 + srow) * H_ + scol;
  const bf16* bg = Wt + (size_t)(n0 + w * 16 + srow) * H_ + scol;
  const int aoff = (w * 32) * 32;
  const int boff = (w * 16) * 32;

  auto stage = [&](int buf, int kk) {
    bf16* ad = As + buf * 4096 + aoff;
    bf16* bd = Bs + buf * 2048 + boff;
    async_ld16(ad,           ag + kk);
    async_ld16(ad + 16 * 32, ag + kk + (size_t)16 * H_);
    async_ld16(bd,           bg + kk);
  };

  const f32x4 z4 = {0.f, 0.f, 0.f, 0.f};
  f32x4 acc[4][2];
  #pragma unroll
  for (int i = 0; i < 4; ++i)
    #pragma unroll
    for (int j = 0; j < 2; ++j) acc[i][j] = z4;

  stage(0, 0);
  __syncthreads();
  int cur = 0;
  for (int k0 = 0; k0 < H_; k0 += 32) {
    if (k0 + 32 < H_) stage(cur ^ 1, k0 + 32);
    const bf16* Ab = As + cur * 4096;
    const bf16* Bb = Bs + cur * 2048;
    bf16x8 af[4], bv[2];
    #pragma unroll
    for (int i = 0; i < 4; ++i)
      af[i] = *(const bf16x8*)(Ab + (wm * 64 + i * 16 + lr) * 32 + lg * 8);
    #pragma unroll
    for (int j = 0; j < 2; ++j)
      bv[j] = *(const bf16x8*)(Bb + (wn * 32 + j * 16 + lr) * 32 + lg * 8);
    #pragma unroll
    for (int i = 0; i < 4; ++i)
      #pragma unroll
      for (int j = 0; j < 2; ++j)
        acc[i][j] = __builtin_amdgcn_mfma_f32_16x16x32_bf16(af[i], bv[j], acc[i][j], 0, 0, 0);
    __syncthreads();
    cur ^= 1;
  }

  if (n0 < 2048) {  // Q or K: direct [B,S,H] store
    bf16* out = (n0 < 1024) ? qo : ko;
    const float* bias = (n0 < 1024) ? bq : bk;
    const int nl = n0 & 1023;
    #pragma unroll
    for (int i = 0; i < 4; ++i) {
      const int row0 = m0 + wm * 64 + i * 16 + lg * 4;
      #pragma unroll
      for (int j = 0; j < 2; ++j) {
        const int col = nl + wn * 32 + j * 16 + lr;
        const float bvx = bias[col];
        #pragma unroll
        for (int r = 0; r < 4; ++r)
          out[(size_t)(row0 + r) * H_ + col] = (bf16)(acc[i][j][r] + bvx);
      }
    }
  } else {          // V: transposed store Vt[((b*NH+h)*DH+d)*S + s]
    const int hh = (n0 >> 6) - 32;
    #pragma unroll
    for (int i = 0; i < 4; ++i) {
      const int row0 = m0 + wm * 64 + i * 16 + lg * 4;
      const int bb = row0 >> 10, ss = row0 & (S_ - 1);
      #pragma unroll
      for (int j = 0; j < 2; ++j) {
        const int dd = wn * 32 + j * 16 + lr;
        const float bvx = bvv[hh * 64 + dd];
        bf16x4 pk;
        #pragma unroll
        for (int r = 0; r < 4; ++r) pk[r] = (bf16)(acc[i][j][r] + bvx);
        *(bf16x4*)(vt + (((size_t)(bb * NH_ + hh) * DH_ + dd) << 10) + ss) = pk;
      }
    }
  }
}

// ---------------- flash attention v7: LDS-staged K/V + mask reg-pipeline ------
__global__ __launch_bounds__(256) void attn_kernel7(
    const bf16* __restrict__ Q, const bf16* __restrict__ Kb,
    const bf16* __restrict__ Vt, const bf16* __restrict__ madd,
    bf16* __restrict__ Ctx) {
  const int tid = (int)threadIdx.x;
  const int w = tid >> 6, l = tid & 63;
  const int lr = l & 15, lg = l >> 4;
  const int r7 = lr & 7;
  const int h = blockIdx.y, b = blockIdx.z;
  const int q0 = blockIdx.x * 64 + w * 16;

  __shared__ __align__(16) bf16 Kt[2][64 * 64];  // [buf][kv][d] swizzled
  __shared__ __align__(16) bf16 Vs[2][64 * 64];  // [buf][d][kv] swizzled
  __shared__ unsigned int Pu[4][16][36];         // per-wave P, u32-packed bf16

  const bf16* qp = Q + ((size_t)(b * S_ + q0 + lr)) * H_ + h * DH_;
  const bf16x8 qa0 = *(const bf16x8*)(qp + lg * 8);
  const bf16x8 qa1 = *(const bf16x8*)(qp + 32 + lg * 8);

  const f32x4 z4 = {0.f, 0.f, 0.f, 0.f};
  f32x4 acc[4];
  #pragma unroll
  for (int dt = 0; dt < 4; ++dt) acc[dt] = z4;
  float mrow = -1e30f, ssum = 0.f;

  const bf16* Kbase = Kb + ((size_t)b * S_) * H_ + h * DH_;
  const bf16* Vbase = Vt + ((size_t)(b * NH_ + h)) * DH_ * S_;
  const bf16* Mb = madd + ((size_t)(b * S_ + q0 + lr)) * S_;

  const float c1 = 0.125f * 1.44269504088896f;   // scale * log2(e)
  const float THR = 10.f;                        // defer-max headroom (base-2)

  const int sub = l >> 3;
  const int cs  = ((l & 7) ^ sub) * 8;
  auto stage = [&](int buf, int kv) {
    #pragma unroll
    for (int j = 0; j < 2; ++j) {
      const int rbase = w * 16 + j * 8;
      async_ld16(&Kt[buf][rbase * 64],
                 Kbase + (size_t)(kv + rbase + sub) * H_ + cs);
      async_ld16(&Vs[buf][rbase * 64],
                 Vbase + (size_t)(rbase + sub) * S_ + kv + cs);
    }
  };

  stage(0, 0);
  bf16x4 mk[4];
  #pragma unroll
  for (int t = 0; t < 4; ++t) mk[t] = *(const bf16x4*)(Mb + t * 16 + lg * 4);
  __syncthreads();                    // vmcnt(0) drain: tile 0 ready
  int cur = 0;
  #pragma unroll 1
  for (int it = 0; it < 16; ++it) {
    const int kv0 = it * 64;
    if (it < 15) stage(cur ^ 1, kv0 + 64);   // async prefetch next K/V tile
    bf16x4 mkn[4];
    if (it < 15) {
      #pragma unroll
      for (int t = 0; t < 4; ++t)
        mkn[t] = *(const bf16x4*)(Mb + kv0 + 64 + t * 16 + lg * 4);
    }
    const bf16* Kc = &Kt[cur][0];
    const bf16* Vc = &Vs[cur][0];
    bf16x8 kf0[4], kf1[4];
    #pragma unroll
    for (int t = 0; t < 4; ++t) {
      kf0[t] = *(const bf16x8*)(Kc + (t * 16 + lr) * 64 + ((lg ^ r7) * 8));
      kf1[t] = *(const bf16x8*)(Kc + (t * 16 + lr) * 64 + (((4 + lg) ^ r7) * 8));
    }
    f32x4 st[4];
    __builtin_amdgcn_s_setprio(1);
    #pragma unroll
    for (int t = 0; t < 4; ++t) {
      f32x4 s = __builtin_amdgcn_mfma_f32_16x16x32_bf16(kf0[t], qa0, z4, 0, 0, 0);
      st[t] = __builtin_amdgcn_mfma_f32_16x16x32_bf16(kf1[t], qa1, s, 0, 0, 0);
    }
    __builtin_amdgcn_s_setprio(0);
    float sv[4][4];
    #pragma unroll
    for (int t = 0; t < 4; ++t)
      #pragma unroll
      for (int r = 0; r < 4; ++r)
        sv[t][r] = st[t][r] * c1 + (float)mk[t][r];
    float nm = sv[0][0];
    #pragma unroll
    for (int t = 0; t < 4; ++t)
      #pragma unroll
      for (int r = 0; r < 4; ++r) nm = fmaxf(nm, sv[t][r]);
    nm = fmaxf(nm, __shfl_xor(nm, 16));
    nm = fmaxf(nm, __shfl_xor(nm, 32));
    if (__any(nm > mrow + THR)) {
      float newm = fmaxf(mrow, nm);
      float f = __builtin_amdgcn_exp2f(mrow - newm);
      mrow = newm;
      ssum *= f;
      #pragma unroll
      for (int dt = 0; dt < 4; ++dt)
        #pragma unroll
        for (int r = 0; r < 4; ++r) acc[dt][r] *= f;
    }
    float p[4][4];
    float ps = 0.f;
    #pragma unroll
    for (int t = 0; t < 4; ++t)
      #pragma unroll
      for (int r = 0; r < 4; ++r) {
        p[t][r] = __builtin_amdgcn_exp2f(sv[t][r] - mrow);
        ps += p[t][r];
      }
    ps += __shfl_xor(ps, 16);
    ps += __shfl_xor(ps, 32);
    ssum += ps;
    #pragma unroll
    for (int t = 0; t < 4; ++t)
      #pragma unroll
      for (int hh = 0; hh < 2; ++hh) {
        union { bf16x2 v; unsigned int u; } pk;
        pk.v[0] = (bf16)p[t][2 * hh];
        pk.v[1] = (bf16)p[t][2 * hh + 1];
        Pu[w][lr][8 * t + 2 * lg + hh] = pk.u;
      }
    const bf16x8 pf0 = *(const bf16x8*)&Pu[w][lr][4 * lg];
    const bf16x8 pf1 = *(const bf16x8*)&Pu[w][lr][16 + 4 * lg];
    __builtin_amdgcn_s_setprio(1);
    #pragma unroll
    for (int dt = 0; dt < 4; ++dt) {
      bf16x8 vb0 = *(const bf16x8*)(Vc + (dt * 16 + lr) * 64 + ((lg ^ r7) * 8));
      acc[dt] = __builtin_amdgcn_mfma_f32_16x16x32_bf16(vb0, pf0, acc[dt], 0, 0, 0);
    }
    #pragma unroll
    for (int dt = 0; dt < 4; ++dt) {
      bf16x8 vb1 = *(const bf16x8*)(Vc + (dt * 16 + lr) * 64 + (((4 + lg) ^ r7) * 8));
      acc[dt] = __builtin_amdgcn_mfma_f32_16x16x32_bf16(vb1, pf1, acc[dt], 0, 0, 0);
    }
    __builtin_amdgcn_s_setprio(0);
    if (it < 15) {
      #pragma unroll
      for (int t = 0; t < 4; ++t) mk[t] = mkn[t];
    }
    __syncthreads();                  // drains prefetch (next tile ready), frees cur
    cur ^= 1;
  }
  const float inv = 1.f / ssum;
  bf16* cp = Ctx + ((size_t)(b * S_ + q0 + lr)) * H_ + h * DH_;
  #pragma unroll
  for (int dt = 0; dt < 4; ++dt) {
    bf16x4 o;
    #pragma unroll
    for (int r = 0; r < 4; ++r) o[r] = (bf16)(acc[dt][r] * inv);
    *(bf16x4*)(cp + dt * 16 + lg * 4) = o;
  }
}

// ---------------- launcher ----------------------------------------------------
extern "C" void kernel_launch(void* const* d_in, const int* in_sizes, int n_in,
                              void* d_out, int out_size, void* d_ws, size_t ws_size,
                              hipStream_t stream) {
  (void)in_sizes; (void)n_in; (void)out_size; (void)ws_size;
  const float* x    = (const float*)d_in[0];
  const float* mask = (const float*)d_in[1];
  const float* wq   = (const float*)d_in[2];
  const float* bq   = (const float*)d_in[3];
  const float* wk   = (const float*)d_in[4];
  const float* bk   = (const float*)d_in[5];
  const float* wv   = (const float*)d_in[6];
  const float* bv   = (const float*)d_in[7];
  const float* wo   = (const float*)d_in[8];
  const float* bo   = (const float*)d_in[9];
  const float* aat  = (const float*)d_in[10];
  const float* wi   = (const float*)d_in[11];
  const float* bi   = (const float*)d_in[12];
  const float* wf   = (const float*)d_in[13];
  const float* bf_  = (const float*)d_in[14];
  const float* afn  = (const float*)d_in[15];

  char* ws = (char*)d_ws;
  size_t o = 0;
  bf16* WtQKV = (bf16*)(ws + o); o += (size_t)L_ * 3 * H_ * H_ * 2; // 24MB
  bf16* WtO = (bf16*)(ws + o); o += (size_t)L_ * H_ * H_ * 2;       //  8MB
  bf16* WtI = (bf16*)(ws + o); o += (size_t)L_ * H_ * F_ * 2;       // 32MB
  bf16* WtF = (bf16*)(ws + o); o += (size_t)L_ * F_ * H_ * 2;       // 32MB
  bf16* madd = (bf16*)(ws + o); o += (size_t)B_ * S_ * S_ * 2;      //  4MB
  bf16* xb  = (bf16*)(ws + o); o += (size_t)M_ * H_ * 2;            //  4MB
  bf16* qb  = (bf16*)(ws + o); o += (size_t)M_ * H_ * 2;
  bf16* kbf = (bf16*)(ws + o); o += (size_t)M_ * H_ * 2;
  bf16* vt  = (bf16*)(ws + o); o += (size_t)M_ * H_ * 2;
  bf16* ctx = (bf16*)(ws + o); o += (size_t)M_ * H_ * 2;
  bf16* itm = (bf16*)(ws + o); o += (size_t)M_ * F_ * 2;            // 16MB
  bf16* partb = (bf16*)(ws + o); o += (size_t)4 * M_ * H_ * 2;      // 16MB

  float* xf = (float*)d_out;  // running x lives in d_out (fp32)

  const size_t HH = (size_t)H_ * H_;
  transpose_all<<<dim3(3072), 256, 0, stream>>>(
      wq, wk, wv, wo, wi, wf, WtQKV, WtO, WtI, WtF);
  prep_kernel<<<dim3(4096), 256, 0, stream>>>(
      (const float4*)mask, (bf16x4*)madd, (const float4*)x, (float4*)xf,
      (bf16x4*)xb);

  for (int l = 0; l < L_; ++l) {
    gemm_qkv64<<<dim3(48, M_/128), 256, 0, stream>>>(
        xb, WtQKV + (size_t)l * 3 * HH,
        bq + l * H_, bk + l * H_, bv + l * H_, qb, kbf, vt);
    attn_kernel7<<<dim3(S_/64, NH_, B_), 256, 0, stream>>>(
        qb, kbf, vt, madd, ctx);
    gemm128_kernel<3><<<dim3(H_/128, M_/128, 4), 256, 0, stream>>>(
        ctx, WtO + (size_t)l * HH, nullptr, partb, H_, H_, H_ / 4);
    reduce_residual<<<dim3((M_ * H_ / 4) / 256), 256, 0, stream>>>(
        (const bf16x4*)partb, bo + l * H_, aat + l, (float4*)xf, (bf16x4*)xb);
    gemm128_kernel<1><<<dim3(F_/128, M_/128), 256, 0, stream>>>(
        xb, WtI + (size_t)l * H_ * F_, bi + l * F_, itm, F_, H_, H_);
    gemm128_kernel<3><<<dim3(H_/128, M_/128, 4), 256, 0, stream>>>(
        itm, WtF + (size_t)l * F_ * H_, nullptr, partb, H_, F_, F_ / 4);
    reduce_residual<<<dim3((M_ * H_ / 4) / 256), 256, 0, stream>>>(
        (const bf16x4*)partb, bf_ + l * H_, afn + l, (float4*)xf, (bf16x4*)xb);
  }
}